// Round 1
// baseline (324.680 us; speedup 1.0000x reference)
//
#include <hip/hip_runtime.h>
#include <hip/hip_bf16.h>
#include <cstdint>

// B=4, S=2048, D=768, H=12, DK=64. All fp32 in/out; bf16 MFMA compute inside.
static constexpr int B_ = 4, S_ = 2048, D_ = 768, H_ = 12, DK_ = 64;
static constexpr int M_ = B_ * S_;  // 8192 rows of x / attn

typedef short bf16x8 __attribute__((ext_vector_type(8)));   // 8 bf16 = 4 VGPRs
typedef float f32x4 __attribute__((ext_vector_type(4)));

#define MFMA16(a, b, c) __builtin_amdgcn_mfma_f32_16x16x32_bf16((a), (b), (c), 0, 0, 0)

__device__ inline ushort f2bf(float f) {
  uint32_t u = __float_as_uint(f);
  u += 0x7fffu + ((u >> 16) & 1u);  // round-nearest-even
  return (ushort)(u >> 16);
}

// ---------------- fp32 -> bf16 convert (8 elems/thread, 16B store) ----------
__global__ void cvt_f32_bf16(const float* __restrict__ in, ushort* __restrict__ out, int n8) {
  int i = blockIdx.x * 256 + threadIdx.x;
  if (i >= n8) return;
  const float4* p = (const float4*)in;
  float4 v0 = p[2 * i], v1 = p[2 * i + 1];
  uint32_t a = (uint32_t)f2bf(v0.x) | ((uint32_t)f2bf(v0.y) << 16);
  uint32_t b = (uint32_t)f2bf(v0.z) | ((uint32_t)f2bf(v0.w) << 16);
  uint32_t c = (uint32_t)f2bf(v1.x) | ((uint32_t)f2bf(v1.y) << 16);
  uint32_t d = (uint32_t)f2bf(v1.z) | ((uint32_t)f2bf(v1.w) << 16);
  ((uint4*)out)[i] = make_uint4(a, b, c, d);
}

// ---------------- GEMM: C[M,N] = A[M,K] @ W[N,K]^T + bias ------------------
// MODE 0: out bf16, layout [b,h,s,dk]  (Q, K)
// MODE 1: out bf16, layout [b,h,dk,s]  (V transposed, for PV MFMA B-operand)
// MODE 2: out fp32, row-major [M,N]    (final output)
template <int MODE>
__global__ __launch_bounds__(256) void gemm_bt(const ushort* __restrict__ A,
                                               const ushort* __restrict__ Bw,
                                               const float* __restrict__ bias,
                                               void* __restrict__ outp) {
  constexpr int K = D_;   // 768
  constexpr int BK = 32;
  __shared__ ushort As[128 * BK];
  __shared__ ushort Bs[128 * BK];

  const int tid = threadIdx.x;
  const int lane = tid & 63, w = tid >> 6;
  const int wr = w >> 1, wc = w & 1;           // 2x2 waves, each 64x64
  const int l15 = lane & 15, l4 = lane >> 4;
  const int bm = blockIdx.x * 128, bn = blockIdx.y * 128;

  f32x4 acc[4][4] = {};

  for (int k0 = 0; k0 < K; k0 += BK) {
    __syncthreads();
#pragma unroll
    for (int i = 0; i < 2; ++i) {               // 128*32 bf16 per tile, 16B/thread/iter
      int e = (i * 256 + tid) * 8;
      int r = e >> 5, c = e & 31;
      *(uint4*)&As[e] = *(const uint4*)&A[(bm + r) * K + k0 + c];
      *(uint4*)&Bs[e] = *(const uint4*)&Bw[(bn + r) * K + k0 + c];
    }
    __syncthreads();
    bf16x8 a[4], b[4];
#pragma unroll
    for (int mi = 0; mi < 4; ++mi)
      a[mi] = *(const bf16x8*)&As[(wr * 64 + mi * 16 + l15) * BK + l4 * 8];
#pragma unroll
    for (int ni = 0; ni < 4; ++ni)
      b[ni] = *(const bf16x8*)&Bs[(wc * 64 + ni * 16 + l15) * BK + l4 * 8];
#pragma unroll
    for (int mi = 0; mi < 4; ++mi)
#pragma unroll
      for (int ni = 0; ni < 4; ++ni)
        acc[mi][ni] = MFMA16(a[mi], b[ni], acc[mi][ni]);
  }

  // Epilogue. C/D layout: col = lane&15, row = (lane>>4)*4 + reg  [m89-verified]
#pragma unroll
  for (int mi = 0; mi < 4; ++mi) {
#pragma unroll
    for (int ni = 0; ni < 4; ++ni) {
      int col = bn + wc * 64 + ni * 16 + l15;
      float bv = bias[col];
#pragma unroll
      for (int r = 0; r < 4; ++r) {
        int row = bm + wr * 64 + mi * 16 + l4 * 4 + r;
        float v = acc[mi][ni][r] + bv;
        if (MODE == 0) {
          int bb = row >> 11, s = row & 2047;
          int h = col >> 6, dk = col & 63;
          ((ushort*)outp)[(((bb * H_ + h) * S_ + s) << 6) + dk] = f2bf(v);
        } else if (MODE == 1) {
          int bb = row >> 11, s = row & 2047;
          int h = col >> 6, dk = col & 63;
          ((ushort*)outp)[(((bb * H_ + h) << 6) + dk) * S_ + s] = f2bf(v);
        } else {
          ((float*)outp)[row * D_ + col] = v;
        }
      }
    }
  }
}

// ---------------- causal flash attention --------------------------------
// grid (B*H, S/64), 256 threads = 4 independent waves; wave owns 16 q-rows.
// Q,K: [bh, s, 64] bf16.  Vt: [bh, 64, s] bf16.  Out: attn [b, s, h*64+dk] bf16.
__global__ __launch_bounds__(256) void attn_fwd(const ushort* __restrict__ Q,
                                                const ushort* __restrict__ Kg,
                                                const ushort* __restrict__ Vt,
                                                ushort* __restrict__ Oa) {
  const int bh = blockIdx.x, qt = blockIdx.y;
  const int w = threadIdx.x >> 6, lane = threadIdx.x & 63;
  const int l15 = lane & 15, l4 = lane >> 4;
  const int q0 = qt * 64 + w * 16;

  const ushort* Qb = Q + (size_t)bh * (S_ * DK_);
  const ushort* Kb = Kg + (size_t)bh * (S_ * DK_);
  const ushort* Vb = Vt + (size_t)bh * (DK_ * S_);

  // Q fragment: A-operand, lane = row l15, k-chunk (l4*8); two 32-wide k chunks
  bf16x8 qf0 = *(const bf16x8*)&Qb[(q0 + l15) * 64 + l4 * 8];
  bf16x8 qf1 = *(const bf16x8*)&Qb[(q0 + l15) * 64 + 32 + l4 * 8];

  f32x4 o[4] = {};                       // O cols d = n*16 + l15, rows l4*4+r
  float mrow[4] = {-__builtin_inff(), -__builtin_inff(), -__builtin_inff(), -__builtin_inff()};
  float lrow[4] = {0.f, 0.f, 0.f, 0.f};

  __shared__ ushort Plds[4][16 * 32];    // per-wave P transpose staging (1KB each)
  ushort* Pw = Plds[w];

  const float SC = 0.125f * 1.4426950408889634f;  // 1/sqrt(64) * log2(e)

  const int nkt = (q0 + 15) / 32 + 1;
  for (int kt = 0; kt < nkt; ++kt) {
    const int k0 = kt * 32;
    // S = Q K^T   (S[q][key]: row = l4*4+r (q), col = l15 + 16f (key))
    f32x4 s[2];
#pragma unroll
    for (int f = 0; f < 2; ++f) {
      bf16x8 ka = *(const bf16x8*)&Kb[(k0 + f * 16 + l15) * 64 + l4 * 8];
      bf16x8 kb = *(const bf16x8*)&Kb[(k0 + f * 16 + l15) * 64 + 32 + l4 * 8];
      f32x4 z = {};
      z = MFMA16(qf0, ka, z);
      z = MFMA16(qf1, kb, z);
      s[f] = z;
    }
    const bool full = (k0 + 31 <= q0);   // tile entirely below diagonal
    float sv[2][4];
#pragma unroll
    for (int f = 0; f < 2; ++f)
#pragma unroll
      for (int r = 0; r < 4; ++r) {
        float v = s[f][r] * SC;
        if (!full) {
          int qg = q0 + l4 * 4 + r, kg = k0 + f * 16 + l15;
          if (kg > qg) v = -__builtin_inff();
        }
        sv[f][r] = v;
      }
    // row max over 32 keys: per-lane pair max, then 16-lane xor reduce
    float pm[4];
#pragma unroll
    for (int r = 0; r < 4; ++r) pm[r] = fmaxf(sv[0][r], sv[1][r]);
#pragma unroll
    for (int off = 1; off <= 8; off <<= 1)
#pragma unroll
      for (int r = 0; r < 4; ++r) pm[r] = fmaxf(pm[r], __shfl_xor(pm[r], off, 64));
    float alpha[4];
#pragma unroll
    for (int r = 0; r < 4; ++r) {
      float nm = fmaxf(mrow[r], pm[r]);
      alpha[r] = exp2f(mrow[r] - nm);    // exp2(-inf)=0 on first tile
      mrow[r] = nm;
    }
    float p[2][4];
    float rs[4] = {0.f, 0.f, 0.f, 0.f};
#pragma unroll
    for (int f = 0; f < 2; ++f)
#pragma unroll
      for (int r = 0; r < 4; ++r) {
        p[f][r] = exp2f(sv[f][r] - mrow[r]);   // masked -> exp2(-inf)=0
        rs[r] += p[f][r];
      }
#pragma unroll
    for (int off = 1; off <= 8; off <<= 1)
#pragma unroll
      for (int r = 0; r < 4; ++r) rs[r] += __shfl_xor(rs[r], off, 64);
#pragma unroll
    for (int r = 0; r < 4; ++r) lrow[r] = lrow[r] * alpha[r] + rs[r];
#pragma unroll
    for (int n = 0; n < 4; ++n)
#pragma unroll
      for (int r = 0; r < 4; ++r) o[n][r] *= alpha[r];

    // P (16x32) -> LDS, re-read in A-operand layout (same wave: lgkmcnt only)
#pragma unroll
    for (int f = 0; f < 2; ++f)
#pragma unroll
      for (int r = 0; r < 4; ++r)
        Pw[(l4 * 4 + r) * 32 + f * 16 + l15] = f2bf(p[f][r]);
    bf16x8 pf = *(const bf16x8*)&Pw[l15 * 32 + l4 * 8];

    // O += P V : B-operand from Vt (col d = l15+16n, key-run l4*8 contiguous)
#pragma unroll
    for (int n = 0; n < 4; ++n) {
      bf16x8 vf = *(const bf16x8*)&Vb[(n * 16 + l15) * S_ + k0 + l4 * 8];
      o[n] = MFMA16(pf, vf, o[n]);
    }
  }

  const int bb = bh / H_, h = bh % H_;
#pragma unroll
  for (int r = 0; r < 4; ++r) {
    float inv = 1.0f / lrow[r];
    int qg = q0 + l4 * 4 + r;
    size_t base = ((size_t)bb * S_ + qg) * D_ + h * DK_;
#pragma unroll
    for (int n = 0; n < 4; ++n) Oa[base + n * 16 + l15] = f2bf(o[n][r] * inv);
  }
}

// ---------------------------------------------------------------------------
extern "C" void kernel_launch(void* const* d_in, const int* in_sizes, int n_in,
                              void* d_out, int out_size, void* d_ws, size_t ws_size,
                              hipStream_t stream) {
  const float* x  = (const float*)d_in[0];
  const float* wq = (const float*)d_in[1];
  const float* bq = (const float*)d_in[2];
  const float* wk = (const float*)d_in[3];
  const float* bk = (const float*)d_in[4];
  const float* wv = (const float*)d_in[5];
  const float* bv = (const float*)d_in[6];
  const float* wo = (const float*)d_in[7];
  const float* bo = (const float*)d_in[8];

  const size_t XB = (size_t)M_ * D_;   // 6,291,456
  const size_t WB = (size_t)D_ * D_;   //   589,824
  ushort* xb    = (ushort*)d_ws;
  ushort* wqb   = xb + XB;
  ushort* wkb   = wqb + WB;
  ushort* wvb   = wkb + WB;
  ushort* wob   = wvb + WB;
  ushort* qb    = wob + WB;
  ushort* kbuf  = qb + XB;
  ushort* vtb   = kbuf + XB;
  ushort* attnb = vtb + XB;            // total ~67.6 MB

  cvt_f32_bf16<<<(int)(XB / 8 / 256), 256, 0, stream>>>(x, xb, (int)(XB / 8));
  cvt_f32_bf16<<<(int)(WB / 8 / 256), 256, 0, stream>>>(wq, wqb, (int)(WB / 8));
  cvt_f32_bf16<<<(int)(WB / 8 / 256), 256, 0, stream>>>(wk, wkb, (int)(WB / 8));
  cvt_f32_bf16<<<(int)(WB / 8 / 256), 256, 0, stream>>>(wv, wvb, (int)(WB / 8));
  cvt_f32_bf16<<<(int)(WB / 8 / 256), 256, 0, stream>>>(wo, wob, (int)(WB / 8));

  dim3 g(M_ / 128, D_ / 128);  // (64, 6)
  gemm_bt<0><<<g, 256, 0, stream>>>(xb, wqb, bq, qb);
  gemm_bt<0><<<g, 256, 0, stream>>>(xb, wkb, bk, kbuf);
  gemm_bt<1><<<g, 256, 0, stream>>>(xb, wvb, bv, vtb);
  attn_fwd<<<dim3(B_ * H_, S_ / 64), 256, 0, stream>>>(qb, kbuf, vtb, attnb);
  gemm_bt<2><<<g, 256, 0, stream>>>(attnb, wob, bo, d_out);
}

// Round 2
// 239.573 us; speedup vs baseline: 1.3552x; 1.3552x over previous
//
#include <hip/hip_runtime.h>
#include <hip/hip_bf16.h>
#include <cstdint>

// B=4, S=2048, D=768, H=12, DK=64. All fp32 in/out; bf16 MFMA compute inside.
static constexpr int B_ = 4, S_ = 2048, D_ = 768, H_ = 12, DK_ = 64;
static constexpr int M_ = B_ * S_;  // 8192 rows of x / attn

typedef short bf16x8 __attribute__((ext_vector_type(8)));   // 8 bf16 = 4 VGPRs
typedef float f32x4 __attribute__((ext_vector_type(4)));
typedef float f32x16 __attribute__((ext_vector_type(16)));
typedef int i32x4 __attribute__((ext_vector_type(4)));

#define MFMA16(a, b, c) __builtin_amdgcn_mfma_f32_16x16x32_bf16((a), (b), (c), 0, 0, 0)
#define MFMA32(a, b, c) __builtin_amdgcn_mfma_f32_32x32x16_bf16((a), (b), (c), 0, 0, 0)

__device__ inline ushort f2bf(float f) {
  uint32_t u = __float_as_uint(f);
  u += 0x7fffu + ((u >> 16) & 1u);  // round-nearest-even
  return (ushort)(u >> 16);
}
__device__ inline uint32_t pkbf(float a, float b) {
  return (uint32_t)f2bf(a) | ((uint32_t)f2bf(b) << 16);
}

// ---------------- fp32 -> bf16 convert (8 elems/thread, 16B store) ----------
__global__ void cvt_f32_bf16(const float* __restrict__ in, ushort* __restrict__ out, int n8) {
  int i = blockIdx.x * 256 + threadIdx.x;
  if (i >= n8) return;
  const float4* p = (const float4*)in;
  float4 v0 = p[2 * i], v1 = p[2 * i + 1];
  uint32_t a = pkbf(v0.x, v0.y);
  uint32_t b = pkbf(v0.z, v0.w);
  uint32_t c = pkbf(v1.x, v1.y);
  uint32_t d = pkbf(v1.z, v1.w);
  ((uint4*)out)[i] = make_uint4(a, b, c, d);
}

// ---------------- GEMM: C[M,N] = A[M,K] @ W[N,K]^T + bias ------------------
// MODE 0: out bf16, layout [b,h,s,dk]  (Q, K)
// MODE 1: out bf16, layout [b,h,dk,s]  (V transposed, for PV MFMA A-operand)
// MODE 2: out fp32, row-major [M,N]    (final output)
template <int MODE>
__global__ __launch_bounds__(256) void gemm_bt(const ushort* __restrict__ A,
                                               const ushort* __restrict__ Bw,
                                               const float* __restrict__ bias,
                                               void* __restrict__ outp) {
  constexpr int K = D_;   // 768
  constexpr int BK = 32;
  __shared__ ushort As[128 * BK];
  __shared__ ushort Bs[128 * BK];

  const int tid = threadIdx.x;
  const int lane = tid & 63, w = tid >> 6;
  const int wr = w >> 1, wc = w & 1;           // 2x2 waves, each 64x64
  const int l15 = lane & 15, l4 = lane >> 4;
  const int bm = blockIdx.x * 128, bn = blockIdx.y * 128;

  f32x4 acc[4][4] = {};

  for (int k0 = 0; k0 < K; k0 += BK) {
    __syncthreads();
#pragma unroll
    for (int i = 0; i < 2; ++i) {               // 128*32 bf16 per tile, 16B/thread/iter
      int e = (i * 256 + tid) * 8;
      int r = e >> 5, c = e & 31;
      *(uint4*)&As[e] = *(const uint4*)&A[(bm + r) * K + k0 + c];
      *(uint4*)&Bs[e] = *(const uint4*)&Bw[(bn + r) * K + k0 + c];
    }
    __syncthreads();
    bf16x8 a[4], b[4];
#pragma unroll
    for (int mi = 0; mi < 4; ++mi)
      a[mi] = *(const bf16x8*)&As[(wr * 64 + mi * 16 + l15) * BK + l4 * 8];
#pragma unroll
    for (int ni = 0; ni < 4; ++ni)
      b[ni] = *(const bf16x8*)&Bs[(wc * 64 + ni * 16 + l15) * BK + l4 * 8];
#pragma unroll
    for (int mi = 0; mi < 4; ++mi)
#pragma unroll
      for (int ni = 0; ni < 4; ++ni)
        acc[mi][ni] = MFMA16(a[mi], b[ni], acc[mi][ni]);
  }

  // Epilogue. C/D layout: col = lane&15, row = (lane>>4)*4 + reg  [m89-verified]
#pragma unroll
  for (int mi = 0; mi < 4; ++mi) {
#pragma unroll
    for (int ni = 0; ni < 4; ++ni) {
      int col = bn + wc * 64 + ni * 16 + l15;
      float bv = bias[col];
#pragma unroll
      for (int r = 0; r < 4; ++r) {
        int row = bm + wr * 64 + mi * 16 + l4 * 4 + r;
        float v = acc[mi][ni][r] + bv;
        if (MODE == 0) {
          int bb = row >> 11, s = row & 2047;
          int h = col >> 6, dk = col & 63;
          ((ushort*)outp)[(((bb * H_ + h) * S_ + s) << 6) + dk] = f2bf(v);
        } else if (MODE == 1) {
          int bb = row >> 11, s = row & 2047;
          int h = col >> 6, dk = col & 63;
          ((ushort*)outp)[(((bb * H_ + h) << 6) + dk) * S_ + s] = f2bf(v);
        } else {
          ((float*)outp)[row * D_ + col] = v;
        }
      }
    }
  }
}

// ---------------- causal flash attention, swapped-operand 32x32 -------------
// grid (B*H, S/128), 256 threads = 4 independent waves; wave owns 32 q-rows.
// Q,K: [bh, s, 64] bf16.  Vt: [bh, 64, s] bf16.  Out: attn [b, s, h*64+dk] bf16.
//
// QK^T: St = mfma(A=K, B=Q) -> St[key][q], col = lane&31 = q (lane-local rows!)
// PV:   Ot = mfma(A=V^T, B=P^T) -> Ot[d][q], col = lane&31 = q
// So m, l, alpha, 1/l are all lane-local scalars; softmax has ONE cross-lane
// op (shfl_xor 32) per reduce instead of serial shuffle chains.
__global__ __launch_bounds__(256) void attn_fwd2(const ushort* __restrict__ Q,
                                                 const ushort* __restrict__ Kg,
                                                 const ushort* __restrict__ Vt,
                                                 ushort* __restrict__ Oa) {
  const int bh = blockIdx.x;
  const int w = threadIdx.x >> 6, lane = threadIdx.x & 63;
  const int l31 = lane & 31, hi = lane >> 5;
  const int q0 = (blockIdx.y * 4 + w) * 32;

  const ushort* Qb = Q + (size_t)bh * (S_ * DK_);
  const ushort* Kb = Kg + (size_t)bh * (S_ * DK_);
  const ushort* Vb = Vt + (size_t)bh * (DK_ * S_);

  // Q B-fragments: col=lane&31=q, k elem j -> d = kc*16 + hi*8 + j
  bf16x8 qf[4];
#pragma unroll
  for (int kc = 0; kc < 4; ++kc)
    qf[kc] = *(const bf16x8*)&Qb[(q0 + l31) * 64 + kc * 16 + hi * 8];

  f32x16 ot[2] = {};                 // O^T tiles: row d = (r&3)+8*(r>>2)+4*hi (+32t), col q=l31
  float m = -__builtin_inff(), l = 0.f;
  const float C = 0.125f * 1.4426950408889634f;  // 1/sqrt(64) * log2(e)
  const float THR = 8.0f / C;                     // defer-max threshold (raw units)

  const int nkt = q0 / 32 + 1;
  for (int kt = 0; kt < nkt; ++kt) {
    const int k0 = kt * 32;
    // --- St = K Q^T over DK=64 (4 MFMAs, K=16 each) ---
    f32x16 st = {};
#pragma unroll
    for (int kc = 0; kc < 4; ++kc) {
      bf16x8 kf = *(const bf16x8*)&Kb[(k0 + l31) * 64 + kc * 16 + hi * 8];
      st = MFMA32(kf, qf[kc], st);
    }
    // --- causal mask (only the diagonal tile: k0 == q0) ---
    if (kt == nkt - 1) {
#pragma unroll
      for (int r = 0; r < 16; ++r) {
        int kr = (r & 3) + 8 * (r >> 2) + 4 * hi;   // key rel
        if (kr > l31) st[r] = -__builtin_inff();
      }
    }
    // --- row max (15 VALU + 1 shfl) ---
    float pm = st[0];
#pragma unroll
    for (int r = 1; r < 16; ++r) pm = fmaxf(pm, st[r]);
    pm = fmaxf(pm, __shfl_xor(pm, 32, 64));
    // --- defer-max: only rescale when the max grew beyond THR ---
    if (!__all(pm <= m + THR)) {
      float mn = fmaxf(m, pm);
      float al = exp2f((m - mn) * C);
      m = mn;
      l *= al;
#pragma unroll
      for (int t = 0; t < 2; ++t)
#pragma unroll
        for (int r = 0; r < 16; ++r) ot[t][r] *= al;
    }
    // --- p = exp2(s*C - m*C), in place; row sum ---
    const float mc = m * C;
    float rs = 0.f;
#pragma unroll
    for (int r = 0; r < 16; ++r) {
      st[r] = exp2f(fmaf(st[r], C, -mc));
      rs += st[r];
    }
    rs += __shfl_xor(rs, 32, 64);
    l += rs;
    // --- P^T repack to B-fragment layout + PV MFMAs ---
    // lane's p regs hold keys (r&3)+8*(r>>2)+4*hi; B-frag chunk c needs keys
    // 16c + hi*8 + j. Exchange halves with shfl_xor(32) (independent, not serial).
#pragma unroll
    for (int c = 0; c < 2; ++c) {
      uint32_t X0 = pkbf(st[8 * c + 0], st[8 * c + 1]);
      uint32_t X1 = pkbf(st[8 * c + 2], st[8 * c + 3]);
      uint32_t Y0 = pkbf(st[8 * c + 4], st[8 * c + 5]);
      uint32_t Y1 = pkbf(st[8 * c + 6], st[8 * c + 7]);
      uint32_t rX0 = __shfl_xor(X0, 32, 64), rX1 = __shfl_xor(X1, 32, 64);
      uint32_t rY0 = __shfl_xor(Y0, 32, 64), rY1 = __shfl_xor(Y1, 32, 64);
      i32x4 bw;
      bw.x = (int)(hi ? rY0 : X0);
      bw.y = (int)(hi ? rY1 : X1);
      bw.z = (int)(hi ? Y0 : rX0);
      bw.w = (int)(hi ? Y1 : rX1);
      bf16x8 pf = __builtin_bit_cast(bf16x8, bw);
#pragma unroll
      for (int t = 0; t < 2; ++t) {
        bf16x8 vf = *(const bf16x8*)&Vb[(t * 32 + l31) * S_ + k0 + c * 16 + hi * 8];
        ot[t] = MFMA32(vf, pf, ot[t]);
      }
    }
  }

  // ---- epilogue: normalize, transpose via per-wave LDS, coalesced store ----
  __shared__ uint32_t Otl[4][32 * 32];    // per-wave 4KB: [q][32 u32 = 64 bf16]
  uint32_t* Ow = Otl[w];
  const float inv = 1.0f / l;            // lane-local (q = l31)
#pragma unroll
  for (int t = 0; t < 2; ++t)
#pragma unroll
    for (int g = 0; g < 4; ++g)
#pragma unroll
      for (int rp = 0; rp < 2; ++rp) {
        int r0 = 4 * g + 2 * rp;
        int ucol = rp + 4 * g + 2 * hi + 16 * t;   // (d>>1), d = 2rp+8g+4hi+32t
        Ow[l31 * 32 + (ucol ^ ((l31 & 7) << 2))] = pkbf(ot[t][r0] * inv, ot[t][r0 + 1] * inv);
      }
  const int bb = bh / H_, h = bh % H_;
#pragma unroll
  for (int i = 0; i < 4; ++i) {
    int chunk = i * 64 + lane;           // 256 chunks of 16B = 32 rows x 128B
    int q = chunk >> 3, cc = chunk & 7;
    i32x4 v = *(const i32x4*)&Ow[q * 32 + ((cc * 4) ^ ((q & 7) << 2))];
    *(i32x4*)&Oa[((size_t)bb * S_ + q0 + q) * D_ + h * 64 + cc * 8] = v;
  }
}

// ---------------------------------------------------------------------------
extern "C" void kernel_launch(void* const* d_in, const int* in_sizes, int n_in,
                              void* d_out, int out_size, void* d_ws, size_t ws_size,
                              hipStream_t stream) {
  const float* x  = (const float*)d_in[0];
  const float* wq = (const float*)d_in[1];
  const float* bq = (const float*)d_in[2];
  const float* wk = (const float*)d_in[3];
  const float* bk = (const float*)d_in[4];
  const float* wv = (const float*)d_in[5];
  const float* bv = (const float*)d_in[6];
  const float* wo = (const float*)d_in[7];
  const float* bo = (const float*)d_in[8];

  const size_t XB = (size_t)M_ * D_;   // 6,291,456
  const size_t WB = (size_t)D_ * D_;   //   589,824
  ushort* xb    = (ushort*)d_ws;
  ushort* wqb   = xb + XB;
  ushort* wkb   = wqb + WB;
  ushort* wvb   = wkb + WB;
  ushort* wob   = wvb + WB;
  ushort* qb    = wob + WB;
  ushort* kbuf  = qb + XB;
  ushort* vtb   = kbuf + XB;
  ushort* attnb = vtb + XB;            // total ~67.6 MB

  cvt_f32_bf16<<<(int)(XB / 8 / 256), 256, 0, stream>>>(x, xb, (int)(XB / 8));
  cvt_f32_bf16<<<(int)(WB / 8 / 256), 256, 0, stream>>>(wq, wqb, (int)(WB / 8));
  cvt_f32_bf16<<<(int)(WB / 8 / 256), 256, 0, stream>>>(wk, wkb, (int)(WB / 8));
  cvt_f32_bf16<<<(int)(WB / 8 / 256), 256, 0, stream>>>(wv, wvb, (int)(WB / 8));
  cvt_f32_bf16<<<(int)(WB / 8 / 256), 256, 0, stream>>>(wo, wob, (int)(WB / 8));

  dim3 g(M_ / 128, D_ / 128);  // (64, 6)
  gemm_bt<0><<<g, 256, 0, stream>>>(xb, wqb, bq, qb);
  gemm_bt<0><<<g, 256, 0, stream>>>(xb, wkb, bk, kbuf);
  gemm_bt<1><<<g, 256, 0, stream>>>(xb, wvb, bv, vtb);
  attn_fwd2<<<dim3(B_ * H_, S_ / 128), 256, 0, stream>>>(qb, kbuf, vtb, attnb);
  gemm_bt<2><<<g, 256, 0, stream>>>(attnb, wob, bo, d_out);
}

// Round 4
// 196.914 us; speedup vs baseline: 1.6488x; 1.2166x over previous
//
#include <hip/hip_runtime.h>
#include <hip/hip_bf16.h>
#include <cstdint>

// B=4, S=2048, D=768, H=12, DK=64. All fp32 in/out; bf16 MFMA compute inside.
static constexpr int B_ = 4, S_ = 2048, D_ = 768, H_ = 12, DK_ = 64;
static constexpr int M_ = B_ * S_;  // 8192 rows of x / attn

typedef short bf16x8 __attribute__((ext_vector_type(8)));   // 8 bf16 = 4 VGPRs
typedef float f32x4 __attribute__((ext_vector_type(4)));
typedef float f32x16 __attribute__((ext_vector_type(16)));
typedef int i32x4 __attribute__((ext_vector_type(4)));

#define MFMA16(a, b, c) __builtin_amdgcn_mfma_f32_16x16x32_bf16((a), (b), (c), 0, 0, 0)
#define MFMA32(a, b, c) __builtin_amdgcn_mfma_f32_32x32x16_bf16((a), (b), (c), 0, 0, 0)

__device__ inline ushort f2bf(float f) {
  uint32_t u = __float_as_uint(f);
  u += 0x7fffu + ((u >> 16) & 1u);  // round-nearest-even
  return (ushort)(u >> 16);
}
__device__ inline uint32_t pkbf(float a, float b) {
  return (uint32_t)f2bf(a) | ((uint32_t)f2bf(b) << 16);
}
// hardware packed f32->bf16 (RNE), 1 instr instead of ~8
__device__ inline uint32_t cvtpk(float lo, float hi) {
  uint32_t r;
  asm("v_cvt_pk_bf16_f32 %0, %1, %2" : "=v"(r) : "v"(lo), "v"(hi));
  return r;
}
// async global->LDS, 16B per lane
__device__ inline void gload_lds16(const void* g, void* l) {
  __builtin_amdgcn_global_load_lds((const __attribute__((address_space(1))) void*)g,
                                   (__attribute__((address_space(3))) void*)l, 16, 0, 0);
}

// ---------------- fp32 -> bf16 convert (8 elems/thread, 16B store) ----------
__global__ void cvt_f32_bf16(const float* __restrict__ in, ushort* __restrict__ out, int n8) {
  int i = blockIdx.x * 256 + threadIdx.x;
  if (i >= n8) return;
  const float4* p = (const float4*)in;
  float4 v0 = p[2 * i], v1 = p[2 * i + 1];
  ((uint4*)out)[i] = make_uint4(pkbf(v0.x, v0.y), pkbf(v0.z, v0.w),
                                pkbf(v1.x, v1.y), pkbf(v1.z, v1.w));
}

// 4 weight matrices in one launch (blockIdx.y selects)
__global__ void cvtw_f32_bf16(const float* __restrict__ w0, const float* __restrict__ w1,
                              const float* __restrict__ w2, const float* __restrict__ w3,
                              ushort* __restrict__ o0, ushort* __restrict__ o1,
                              ushort* __restrict__ o2, ushort* __restrict__ o3, int n8) {
  const float* in;
  ushort* out;
  switch (blockIdx.y) {
    case 0: in = w0; out = o0; break;
    case 1: in = w1; out = o1; break;
    case 2: in = w2; out = o2; break;
    default: in = w3; out = o3; break;
  }
  int i = blockIdx.x * 256 + threadIdx.x;
  if (i >= n8) return;
  const float4* p = (const float4*)in;
  float4 v0 = p[2 * i], v1 = p[2 * i + 1];
  ((uint4*)out)[i] = make_uint4(pkbf(v0.x, v0.y), pkbf(v0.z, v0.w),
                                pkbf(v1.x, v1.y), pkbf(v1.z, v1.w));
}

// ---------------- GEMM: C[M,N] = A[M,K] @ W[N,K]^T + bias ------------------
// global_load_lds staging (m97 structure). MODE 0: bf16 [b,h,s,dk]; MODE 1:
// bf16 [b,h,dk,s] (V^T); MODE 2: fp32 row-major [M,N].
template <int MODE>
__global__ __launch_bounds__(256) void gemm_bt(const ushort* __restrict__ A,
                                               const ushort* __restrict__ Bw,
                                               const float* __restrict__ bias,
                                               void* __restrict__ outp) {
  constexpr int K = D_;   // 768
  constexpr int BK = 32;
  __shared__ ushort As[128 * BK];
  __shared__ ushort Bs[128 * BK];

  const int tid = threadIdx.x;
  const int lane = tid & 63, w = tid >> 6;
  const int wr = w >> 1, wc = w & 1;           // 2x2 waves, each 64x64
  const int l15 = lane & 15, l4 = lane >> 4;
  const int bm = blockIdx.x * 128, bn = blockIdx.y * 128;

  f32x4 acc[4][4] = {};

  for (int k0 = 0; k0 < K; k0 += BK) {
    __syncthreads();
#pragma unroll
    for (int i = 0; i < 2; ++i) {               // 128*32 bf16 per tile, 16B/lane, LDS dest linear in tid
      int e = (i * 256 + tid) * 8;
      int r = e >> 5, c = e & 31;
      gload_lds16(&A[(size_t)(bm + r) * K + k0 + c], &As[e]);
      gload_lds16(&Bw[(size_t)(bn + r) * K + k0 + c], &Bs[e]);
    }
    __syncthreads();
    bf16x8 a[4], b[4];
#pragma unroll
    for (int mi = 0; mi < 4; ++mi)
      a[mi] = *(const bf16x8*)&As[(wr * 64 + mi * 16 + l15) * BK + l4 * 8];
#pragma unroll
    for (int ni = 0; ni < 4; ++ni)
      b[ni] = *(const bf16x8*)&Bs[(wc * 64 + ni * 16 + l15) * BK + l4 * 8];
    __builtin_amdgcn_s_setprio(1);
#pragma unroll
    for (int mi = 0; mi < 4; ++mi)
#pragma unroll
      for (int ni = 0; ni < 4; ++ni)
        acc[mi][ni] = MFMA16(a[mi], b[ni], acc[mi][ni]);
    __builtin_amdgcn_s_setprio(0);
  }

  // Epilogue. C/D layout: col = lane&15, row = (lane>>4)*4 + reg  [m89-verified]
#pragma unroll
  for (int mi = 0; mi < 4; ++mi) {
#pragma unroll
    for (int ni = 0; ni < 4; ++ni) {
      int col = bn + wc * 64 + ni * 16 + l15;
      float bv = bias[col];
#pragma unroll
      for (int r = 0; r < 4; ++r) {
        int row = bm + wr * 64 + mi * 16 + l4 * 4 + r;
        float v = acc[mi][ni][r] + bv;
        if (MODE == 0) {
          int bb = row >> 11, s = row & 2047;
          int h = col >> 6, dk = col & 63;
          ((ushort*)outp)[(((bb * H_ + h) * S_ + s) << 6) + dk] = f2bf(v);
        } else if (MODE == 1) {
          int bb = row >> 11, s = row & 2047;
          int h = col >> 6, dk = col & 63;
          ((ushort*)outp)[(((bb * H_ + h) << 6) + dk) * S_ + s] = f2bf(v);
        } else {
          ((float*)outp)[row * D_ + col] = v;
        }
      }
    }
  }
}

// ---------------- causal flash attention, swapped-operand 32x32 -------------
// grid (B*H, S/64), 256 threads = 4 waves = 2 q-tiles x 2 KV-splits.
// Wave pair (sp=0,1) shares 32 q-rows; sp s handles key-tiles [s*nkt/2,(s+1)*nkt/2).
// Heavy-first dispatch: qt = gridDim.y-1-blockIdx.y.
// QK^T: St = mfma(A=K, B=Q) -> St[key][q], col q = lane&31 (lane-local softmax)
// PV:   Ot = mfma(A=V^T, B=P^T) -> Ot[d][q]
__global__ __launch_bounds__(256) void attn_fwd3(const ushort* __restrict__ Q,
                                                 const ushort* __restrict__ Kg,
                                                 const ushort* __restrict__ Vt,
                                                 ushort* __restrict__ Oa) {
  const int bh = blockIdx.x;
  const int w = threadIdx.x >> 6, lane = threadIdx.x & 63;
  const int l31 = lane & 31, hi = lane >> 5;
  const int pair = w >> 1, sp = w & 1;
  const int qt = gridDim.y - 1 - blockIdx.y;       // heavy blocks first
  const int q0 = qt * 64 + pair * 32;

  const ushort* Qb = Q + (size_t)bh * (S_ * DK_);
  const ushort* Kb = Kg + (size_t)bh * (S_ * DK_);
  const ushort* Vb = Vt + (size_t)bh * (DK_ * S_);

  // Q B-fragments: col=lane&31=q, k elem j -> d = kc*16 + hi*8 + j
  bf16x8 qf[4];
#pragma unroll
  for (int kc = 0; kc < 4; ++kc)
    qf[kc] = *(const bf16x8*)&Qb[(q0 + l31) * 64 + kc * 16 + hi * 8];

  f32x16 ot[2] = {};                 // O^T: row d=(r&3)+8*(r>>2)+4*hi+32t, col q=l31
  float m = -__builtin_inff(), l = 0.f;
  const float C = 0.125f * 1.4426950408889634f;  // 1/sqrt(64) * log2(e)
  const float THR = 8.0f / C;                    // defer-max threshold (raw units)

  const int nkt = q0 / 32 + 1;
  const int kt_beg = sp ? nkt / 2 : 0;
  const int kt_end = sp ? nkt : nkt / 2;
  for (int kt = kt_beg; kt < kt_end; ++kt) {
    const int k0 = kt * 32;
    // --- St = K Q^T over DK=64 (4 MFMAs) ---
    f32x16 st = {};
    __builtin_amdgcn_s_setprio(1);
#pragma unroll
    for (int kc = 0; kc < 4; ++kc) {
      bf16x8 kf = *(const bf16x8*)&Kb[(k0 + l31) * 64 + kc * 16 + hi * 8];
      st = MFMA32(kf, qf[kc], st);
    }
    __builtin_amdgcn_s_setprio(0);
    // --- causal mask (diagonal tile only) ---
    if (kt == nkt - 1) {
#pragma unroll
      for (int r = 0; r < 16; ++r) {
        int kr = (r & 3) + 8 * (r >> 2) + 4 * hi;
        if (kr > l31) st[r] = -__builtin_inff();
      }
    }
    // --- row max: tree (depth 4) + 1 shfl ---
    float mx[8];
#pragma unroll
    for (int i = 0; i < 8; ++i) mx[i] = fmaxf(st[i], st[i + 8]);
#pragma unroll
    for (int i = 0; i < 4; ++i) mx[i] = fmaxf(mx[i], mx[i + 4]);
    float pm = fmaxf(fmaxf(mx[0], mx[1]), fmaxf(mx[2], mx[3]));
    pm = fmaxf(pm, __shfl_xor(pm, 32, 64));
    // --- defer-max: rescale only when max grew beyond THR ---
    if (!__all(pm <= m + THR)) {
      float mn = fmaxf(m, pm);
      float al = exp2f((m - mn) * C);
      m = mn;
      l *= al;
#pragma unroll
      for (int t = 0; t < 2; ++t)
#pragma unroll
        for (int r = 0; r < 16; ++r) ot[t][r] *= al;
    }
    // --- p = exp2(s*C - m*C) in place; tree row-sum ---
    const float mc = m * C;
#pragma unroll
    for (int r = 0; r < 16; ++r) st[r] = exp2f(fmaf(st[r], C, -mc));
    float sx[8];
#pragma unroll
    for (int i = 0; i < 8; ++i) sx[i] = st[i] + st[i + 8];
#pragma unroll
    for (int i = 0; i < 4; ++i) sx[i] = sx[i] + sx[i + 4];
    float rs = (sx[0] + sx[1]) + (sx[2] + sx[3]);
    rs += __shfl_xor(rs, 32, 64);
    l += rs;
    // --- P^T repack to B-fragment layout (cvt_pk + shfl) + PV MFMAs ---
#pragma unroll
    for (int c = 0; c < 2; ++c) {
      uint32_t X0 = cvtpk(st[8 * c + 0], st[8 * c + 1]);
      uint32_t X1 = cvtpk(st[8 * c + 2], st[8 * c + 3]);
      uint32_t Y0 = cvtpk(st[8 * c + 4], st[8 * c + 5]);
      uint32_t Y1 = cvtpk(st[8 * c + 6], st[8 * c + 7]);
      uint32_t rX0 = __shfl_xor(X0, 32, 64), rX1 = __shfl_xor(X1, 32, 64);
      uint32_t rY0 = __shfl_xor(Y0, 32, 64), rY1 = __shfl_xor(Y1, 32, 64);
      i32x4 bw;
      bw.x = (int)(hi ? rY0 : X0);
      bw.y = (int)(hi ? rY1 : X1);
      bw.z = (int)(hi ? Y0 : rX0);
      bw.w = (int)(hi ? Y1 : rX1);
      bf16x8 pf = __builtin_bit_cast(bf16x8, bw);
      __builtin_amdgcn_s_setprio(1);
#pragma unroll
      for (int t = 0; t < 2; ++t) {
        bf16x8 vf = *(const bf16x8*)&Vb[(t * 32 + l31) * S_ + k0 + c * 16 + hi * 8];
        ot[t] = MFMA32(vf, pf, ot[t]);
      }
      __builtin_amdgcn_s_setprio(0);
    }
  }

  // ---- merge the two KV-splits, then transpose + coalesced store ----
  __shared__ float Om[2][64][32];          // 16 KB: [pair][d][q]
  __shared__ float Ml[2][32], Ll[2][32];
  __shared__ uint32_t Otl[2][32 * 32];     // 8 KB transpose staging

  if (sp == 0) {
#pragma unroll
    for (int t = 0; t < 2; ++t)
#pragma unroll
      for (int r = 0; r < 16; ++r) {
        int d = (r & 3) + 8 * (r >> 2) + 4 * hi + 32 * t;
        Om[pair][d][l31] = ot[t][r];
      }
    if (hi == 0) { Ml[pair][l31] = m; Ll[pair][l31] = l; }
  }
  __syncthreads();
  if (sp == 1) {
    float m0 = Ml[pair][l31], l0 = Ll[pair][l31];
    float M = fmaxf(m, m0);
    float a1 = exp2f((m - M) * C), a0 = exp2f((m0 - M) * C);
    float inv = 1.0f / (a1 * l + a0 * l0);
    a1 *= inv; a0 *= inv;
#pragma unroll
    for (int t = 0; t < 2; ++t)
#pragma unroll
      for (int r = 0; r < 16; ++r) {
        int d = (r & 3) + 8 * (r >> 2) + 4 * hi + 32 * t;
        ot[t][r] = a1 * ot[t][r] + a0 * Om[pair][d][l31];
      }
    uint32_t* Ow = Otl[pair];
#pragma unroll
    for (int t = 0; t < 2; ++t)
#pragma unroll
      for (int g = 0; g < 4; ++g)
#pragma unroll
        for (int rp = 0; rp < 2; ++rp) {
          int r0 = 4 * g + 2 * rp;
          int ucol = rp + 4 * g + 2 * hi + 16 * t;   // (d>>1)
          Ow[l31 * 32 + (ucol ^ ((l31 & 7) << 2))] = cvtpk(ot[t][r0], ot[t][r0 + 1]);
        }
    const int bb = bh / H_, h = bh % H_;
#pragma unroll
    for (int i = 0; i < 4; ++i) {
      int chunk = i * 64 + lane;           // 256 chunks of 16B = 32 rows x 128B
      int q = chunk >> 3, cc = chunk & 7;
      i32x4 v = *(const i32x4*)&Ow[q * 32 + ((cc * 4) ^ ((q & 7) << 2))];
      *(i32x4*)&Oa[((size_t)bb * S_ + q0 + q) * D_ + h * 64 + cc * 8] = v;
    }
  }
}

// ---------------------------------------------------------------------------
extern "C" void kernel_launch(void* const* d_in, const int* in_sizes, int n_in,
                              void* d_out, int out_size, void* d_ws, size_t ws_size,
                              hipStream_t stream) {
  const float* x  = (const float*)d_in[0];
  const float* wq = (const float*)d_in[1];
  const float* bq = (const float*)d_in[2];
  const float* wk = (const float*)d_in[3];
  const float* bk = (const float*)d_in[4];
  const float* wv = (const float*)d_in[5];
  const float* bv = (const float*)d_in[6];
  const float* wo = (const float*)d_in[7];
  const float* bo = (const float*)d_in[8];

  const size_t XB = (size_t)M_ * D_;   // 6,291,456
  const size_t WB = (size_t)D_ * D_;   //   589,824
  ushort* xb    = (ushort*)d_ws;
  ushort* wqb   = xb + XB;
  ushort* wkb   = wqb + WB;
  ushort* wvb   = wkb + WB;
  ushort* wob   = wvb + WB;
  ushort* qb    = wob + WB;
  ushort* kbuf  = qb + XB;
  ushort* vtb   = kbuf + XB;
  ushort* attnb = vtb + XB;            // total ~67.6 MB

  cvt_f32_bf16<<<(int)(XB / 8 / 256), 256, 0, stream>>>(x, xb, (int)(XB / 8));
  cvtw_f32_bf16<<<dim3((int)(WB / 8 / 256), 4), 256, 0, stream>>>(
      wq, wk, wv, wo, wqb, wkb, wvb, wob, (int)(WB / 8));

  dim3 g(M_ / 128, D_ / 128);  // (64, 6)
  gemm_bt<0><<<g, 256, 0, stream>>>(xb, wqb, bq, qb);
  gemm_bt<0><<<g, 256, 0, stream>>>(xb, wkb, bk, kbuf);
  gemm_bt<1><<<g, 256, 0, stream>>>(xb, wvb, bv, vtb);
  attn_fwd3<<<dim3(B_ * H_, S_ / 64), 256, 0, stream>>>(qb, kbuf, vtb, attnb);
  gemm_bt<2><<<g, 256, 0, stream>>>(attnb, wob, bo, d_out);
}

// Round 5
// 183.584 us; speedup vs baseline: 1.7686x; 1.0726x over previous
//
#include <hip/hip_runtime.h>
#include <hip/hip_bf16.h>
#include <cstdint>

// B=4, S=2048, D=768, H=12, DK=64. All fp32 in/out; bf16 MFMA compute inside.
static constexpr int B_ = 4, S_ = 2048, D_ = 768, H_ = 12, DK_ = 64;
static constexpr int M_ = B_ * S_;  // 8192 rows of x / attn

typedef short bf16x8 __attribute__((ext_vector_type(8)));   // 8 bf16 = 4 VGPRs
typedef float f32x4 __attribute__((ext_vector_type(4)));
typedef float f32x16 __attribute__((ext_vector_type(16)));
typedef int i32x4 __attribute__((ext_vector_type(4)));

#define MFMA16(a, b, c) __builtin_amdgcn_mfma_f32_16x16x32_bf16((a), (b), (c), 0, 0, 0)
#define MFMA32(a, b, c) __builtin_amdgcn_mfma_f32_32x32x16_bf16((a), (b), (c), 0, 0, 0)

__device__ inline ushort f2bf(float f) {
  uint32_t u = __float_as_uint(f);
  u += 0x7fffu + ((u >> 16) & 1u);  // round-nearest-even
  return (ushort)(u >> 16);
}
__device__ inline uint32_t pkbf(float a, float b) {
  return (uint32_t)f2bf(a) | ((uint32_t)f2bf(b) << 16);
}
// hardware packed f32->bf16 (RNE)
__device__ inline uint32_t cvtpk(float lo, float hi) {
  uint32_t r;
  asm("v_cvt_pk_bf16_f32 %0, %1, %2" : "=v"(r) : "v"(lo), "v"(hi));
  return r;
}
// async global->LDS, 16B per lane (LDS dest = wave-uniform base + lane*16)
__device__ inline void gload_lds16(const void* g, void* l) {
  __builtin_amdgcn_global_load_lds((const __attribute__((address_space(1))) void*)g,
                                   (__attribute__((address_space(3))) void*)l, 16, 0, 0);
}

// ---------------- fp32 -> bf16 convert (8 elems/thread, 16B store) ----------
__global__ void cvt_f32_bf16(const float* __restrict__ in, ushort* __restrict__ out, int n8) {
  int i = blockIdx.x * 256 + threadIdx.x;
  if (i >= n8) return;
  const float4* p = (const float4*)in;
  float4 v0 = p[2 * i], v1 = p[2 * i + 1];
  ((uint4*)out)[i] = make_uint4(pkbf(v0.x, v0.y), pkbf(v0.z, v0.w),
                                pkbf(v1.x, v1.y), pkbf(v1.z, v1.w));
}

// 4 weight matrices in one launch (blockIdx.y selects)
__global__ void cvtw_f32_bf16(const float* __restrict__ w0, const float* __restrict__ w1,
                              const float* __restrict__ w2, const float* __restrict__ w3,
                              ushort* __restrict__ o0, ushort* __restrict__ o1,
                              ushort* __restrict__ o2, ushort* __restrict__ o3, int n8) {
  const float* in;
  ushort* out;
  switch (blockIdx.y) {
    case 0: in = w0; out = o0; break;
    case 1: in = w1; out = o1; break;
    case 2: in = w2; out = o2; break;
    default: in = w3; out = o3; break;
  }
  int i = blockIdx.x * 256 + threadIdx.x;
  if (i >= n8) return;
  const float4* p = (const float4*)in;
  float4 v0 = p[2 * i], v1 = p[2 * i + 1];
  ((uint4*)out)[i] = make_uint4(pkbf(v0.x, v0.y), pkbf(v0.z, v0.w),
                                pkbf(v1.x, v1.y), pkbf(v1.z, v1.w));
}

// ---------------- fused QKV GEMM: one launch, N = 3*768 --------------------
// blockIdx.y in [0,18): wsel = y/6 selects {Wq->Q, Wk->K, Wv->V^T}.
// Q/K out: bf16 [b,h,s,dk]. V out: bf16 [b,h,dk,s].
__global__ __launch_bounds__(256) void gemm_qkv(const ushort* __restrict__ A,
                                                const ushort* __restrict__ Wq,
                                                const ushort* __restrict__ Wk,
                                                const ushort* __restrict__ Wv,
                                                const float* __restrict__ bqp,
                                                const float* __restrict__ bkp,
                                                const float* __restrict__ bvp,
                                                ushort* __restrict__ Qo,
                                                ushort* __restrict__ Ko,
                                                ushort* __restrict__ Vo) {
  constexpr int K = D_;   // 768
  constexpr int BK = 32;
  __shared__ ushort As[128 * BK];
  __shared__ ushort Bs[128 * BK];

  const int wsel = blockIdx.y / 6;
  const int bn = (blockIdx.y % 6) * 128;     // col base within this weight
  const ushort* Bw = wsel == 0 ? Wq : wsel == 1 ? Wk : Wv;
  const float* bias = wsel == 0 ? bqp : wsel == 1 ? bkp : bvp;
  ushort* outp = wsel == 0 ? Qo : wsel == 1 ? Ko : Vo;

  const int tid = threadIdx.x;
  const int lane = tid & 63, w = tid >> 6;
  const int wr = w >> 1, wc = w & 1;           // 2x2 waves, each 64x64
  const int l15 = lane & 15, l4 = lane >> 4;
  const int bm = blockIdx.x * 128;

  f32x4 acc[4][4] = {};

  for (int k0 = 0; k0 < K; k0 += BK) {
    __syncthreads();
#pragma unroll
    for (int i = 0; i < 2; ++i) {
      int e = (i * 256 + tid) * 8;
      int r = e >> 5, c = e & 31;
      gload_lds16(&A[(size_t)(bm + r) * K + k0 + c], &As[e]);
      gload_lds16(&Bw[(size_t)(bn + r) * K + k0 + c], &Bs[e]);
    }
    __syncthreads();
    bf16x8 a[4], b[4];
#pragma unroll
    for (int mi = 0; mi < 4; ++mi)
      a[mi] = *(const bf16x8*)&As[(wr * 64 + mi * 16 + l15) * BK + l4 * 8];
#pragma unroll
    for (int ni = 0; ni < 4; ++ni)
      b[ni] = *(const bf16x8*)&Bs[(wc * 64 + ni * 16 + l15) * BK + l4 * 8];
    __builtin_amdgcn_s_setprio(1);
#pragma unroll
    for (int mi = 0; mi < 4; ++mi)
#pragma unroll
      for (int ni = 0; ni < 4; ++ni)
        acc[mi][ni] = MFMA16(a[mi], b[ni], acc[mi][ni]);
    __builtin_amdgcn_s_setprio(0);
  }

#pragma unroll
  for (int mi = 0; mi < 4; ++mi) {
#pragma unroll
    for (int ni = 0; ni < 4; ++ni) {
      int col = bn + wc * 64 + ni * 16 + l15;
      float bv = bias[col];
#pragma unroll
      for (int r = 0; r < 4; ++r) {
        int row = bm + wr * 64 + mi * 16 + l4 * 4 + r;
        float v = acc[mi][ni][r] + bv;
        int bb = row >> 11, s = row & 2047;
        int h = col >> 6, dk = col & 63;
        if (wsel < 2)
          outp[(((bb * H_ + h) * S_ + s) << 6) + dk] = f2bf(v);
        else
          outp[(((bb * H_ + h) << 6) + dk) * S_ + s] = f2bf(v);
      }
    }
  }
}

// ---------------- output GEMM: fp32 out, row-major [M,N] -------------------
__global__ __launch_bounds__(256) void gemm_out(const ushort* __restrict__ A,
                                                const ushort* __restrict__ Bw,
                                                const float* __restrict__ bias,
                                                float* __restrict__ outp) {
  constexpr int K = D_;
  constexpr int BK = 32;
  __shared__ ushort As[128 * BK];
  __shared__ ushort Bs[128 * BK];

  const int tid = threadIdx.x;
  const int lane = tid & 63, w = tid >> 6;
  const int wr = w >> 1, wc = w & 1;
  const int l15 = lane & 15, l4 = lane >> 4;
  const int bm = blockIdx.x * 128, bn = blockIdx.y * 128;

  f32x4 acc[4][4] = {};

  for (int k0 = 0; k0 < K; k0 += BK) {
    __syncthreads();
#pragma unroll
    for (int i = 0; i < 2; ++i) {
      int e = (i * 256 + tid) * 8;
      int r = e >> 5, c = e & 31;
      gload_lds16(&A[(size_t)(bm + r) * K + k0 + c], &As[e]);
      gload_lds16(&Bw[(size_t)(bn + r) * K + k0 + c], &Bs[e]);
    }
    __syncthreads();
    bf16x8 a[4], b[4];
#pragma unroll
    for (int mi = 0; mi < 4; ++mi)
      a[mi] = *(const bf16x8*)&As[(wr * 64 + mi * 16 + l15) * BK + l4 * 8];
#pragma unroll
    for (int ni = 0; ni < 4; ++ni)
      b[ni] = *(const bf16x8*)&Bs[(wc * 64 + ni * 16 + l15) * BK + l4 * 8];
    __builtin_amdgcn_s_setprio(1);
#pragma unroll
    for (int mi = 0; mi < 4; ++mi)
#pragma unroll
      for (int ni = 0; ni < 4; ++ni)
        acc[mi][ni] = MFMA16(a[mi], b[ni], acc[mi][ni]);
    __builtin_amdgcn_s_setprio(0);
  }

#pragma unroll
  for (int mi = 0; mi < 4; ++mi)
#pragma unroll
    for (int ni = 0; ni < 4; ++ni) {
      int col = bn + wc * 64 + ni * 16 + l15;
      float bv = bias[col];
#pragma unroll
      for (int r = 0; r < 4; ++r) {
        int row = bm + wr * 64 + mi * 16 + l4 * 4 + r;
        outp[(size_t)row * D_ + col] = acc[mi][ni][r] + bv;
      }
    }
}

// ---------------- causal flash attention, LDS-staged KV ---------------------
// grid (B*H, S/128), 256 threads = 4 waves, each owns 32 q-rows (block: 128).
// All 4 waves walk the SAME key tiles (KVBLK=64), double-buffered in LDS,
// staged cooperatively with global_load_lds. XOR swizzle (T2, rule #21):
// LDS linear dest + inverse-swizzled global source + swizzled LDS read,
// involution b ^= ((b>>7)&7)<<4 (bits 4-6 from row bits 7-9).
// QK^T: St = mfma(A=K, B=Q) -> col q = lane&31 (lane-local softmax).
// PV:   Ot = mfma(A=V^T, B=P^T) -> col q = lane&31.
__global__ __launch_bounds__(256) void attn_fwd4(const ushort* __restrict__ Q,
                                                 const ushort* __restrict__ Kg,
                                                 const ushort* __restrict__ Vt,
                                                 ushort* __restrict__ Oa) {
  __shared__ ushort KT[2][64 * 64];   // 8KB per buf
  __shared__ ushort VT[2][64 * 64];   // 8KB per buf (V^T tile: [d][key])

  const int bh = blockIdx.x;
  const int w = threadIdx.x >> 6, lane = threadIdx.x & 63;
  const int l31 = lane & 31, hi = lane >> 5;
  const int qtb = gridDim.y - 1 - blockIdx.y;      // heavy blocks first
  const int qb = qtb * 128;
  const int q0 = qb + w * 32;

  const ushort* Qb = Q + (size_t)bh * (S_ * DK_);
  const char* Kc = (const char*)(Kg + (size_t)bh * (S_ * DK_));
  const char* Vc = (const char*)(Vt + (size_t)bh * (DK_ * S_));

  // Q B-fragments: col=lane&31=q, k elem j -> d = kc*16 + hi*8 + j
  bf16x8 qf[4];
#pragma unroll
  for (int kc = 0; kc < 4; ++kc)
    qf[kc] = *(const bf16x8*)&Qb[(q0 + l31) * 64 + kc * 16 + hi * 8];

  f32x16 ot[2] = {};                 // O^T: row d=(r&3)+8*(r>>2)+4*hi+32t, col q=l31
  float m = -__builtin_inff(), l = 0.f;
  const float C = 0.125f * 1.4426950408889634f;  // 1/sqrt(64) * log2(e)
  const float THR = 8.0f / C;

  // stage key-tile kt into buffer buf (this wave's quarter: rows w*16..w*16+15)
  auto stage = [&](int buf, int kt) {
    const int k0 = kt * 64;
#pragma unroll
    for (int i = 0; i < 2; ++i) {
      int obase = w * 2048 + i * 1024;                 // byte offset in 8KB tile
      int o = obase + lane * 16;
      int mk = ((o >> 7) & 7) << 4;                    // swizzle mask from row
      // K: global rows contiguous (key-major, 128B/row)
      gload_lds16(Kc + (size_t)k0 * 128 + (o ^ mk), (char*)&KT[buf][0] + obase);
      // V^T: global rows strided (d-major, S*2 = 4096B/row), gather per lane
      int d = o >> 7;
      int colb = (o & 127) ^ mk;
      gload_lds16(Vc + (size_t)d * 4096 + (size_t)k0 * 2 + colb,
                  (char*)&VT[buf][0] + obase);
    }
  };

  const int nkt = qb / 64 + 2;       // walk keys [0, qb+128)
  int cur = 0;
  stage(0, 0);
  __syncthreads();

  for (int kt = 0; kt < nkt; ++kt) {
    if (kt + 1 < nkt) stage(cur ^ 1, kt + 1);
    const int k0 = kt * 64;
#pragma unroll
    for (int sub = 0; sub < 2; ++sub) {
      const int ks = k0 + sub * 32;
      if (ks <= q0 + 31) {           // wave-uniform; no barrier inside
        // --- St = K Q^T (4 MFMAs), K frags from swizzled LDS ---
        f32x16 st = {};
        __builtin_amdgcn_s_setprio(1);
#pragma unroll
        for (int kc = 0; kc < 4; ++kc) {
          int row = sub * 32 + l31;
          int col = (kc * 32 + hi * 16) ^ ((row & 7) << 4);
          bf16x8 kf = *(const bf16x8*)((const char*)&KT[cur][0] + row * 128 + col);
          st = MFMA32(kf, qf[kc], st);
        }
        __builtin_amdgcn_s_setprio(0);
        // --- causal mask (partial tile only) ---
        if (ks + 31 > q0) {
#pragma unroll
          for (int r = 0; r < 16; ++r) {
            int kr = ks + (r & 3) + 8 * (r >> 2) + 4 * hi;
            if (kr > q0 + l31) st[r] = -__builtin_inff();
          }
        }
        // --- row max: tree + 1 shfl ---
        float mx[8];
#pragma unroll
        for (int i = 0; i < 8; ++i) mx[i] = fmaxf(st[i], st[i + 8]);
#pragma unroll
        for (int i = 0; i < 4; ++i) mx[i] = fmaxf(mx[i], mx[i + 4]);
        float pm = fmaxf(fmaxf(mx[0], mx[1]), fmaxf(mx[2], mx[3]));
        pm = fmaxf(pm, __shfl_xor(pm, 32, 64));
        // --- defer-max rescale ---
        if (!__all(pm <= m + THR)) {
          float mn = fmaxf(m, pm);
          float al = exp2f((m - mn) * C);
          m = mn;
          l *= al;
#pragma unroll
          for (int t = 0; t < 2; ++t)
#pragma unroll
            for (int r = 0; r < 16; ++r) ot[t][r] *= al;
        }
        // --- p = exp2(s*C - m*C); tree row-sum ---
        const float mc = m * C;
#pragma unroll
        for (int r = 0; r < 16; ++r) st[r] = exp2f(fmaf(st[r], C, -mc));
        float sx[8];
#pragma unroll
        for (int i = 0; i < 8; ++i) sx[i] = st[i] + st[i + 8];
#pragma unroll
        for (int i = 0; i < 4; ++i) sx[i] = sx[i] + sx[i + 4];
        float rs = (sx[0] + sx[1]) + (sx[2] + sx[3]);
        rs += __shfl_xor(rs, 32, 64);
        l += rs;
        // --- P^T repack (cvt_pk + shfl) + PV MFMAs from swizzled LDS V ---
#pragma unroll
        for (int c = 0; c < 2; ++c) {
          uint32_t X0 = cvtpk(st[8 * c + 0], st[8 * c + 1]);
          uint32_t X1 = cvtpk(st[8 * c + 2], st[8 * c + 3]);
          uint32_t Y0 = cvtpk(st[8 * c + 4], st[8 * c + 5]);
          uint32_t Y1 = cvtpk(st[8 * c + 6], st[8 * c + 7]);
          uint32_t rX0 = __shfl_xor(X0, 32, 64), rX1 = __shfl_xor(X1, 32, 64);
          uint32_t rY0 = __shfl_xor(Y0, 32, 64), rY1 = __shfl_xor(Y1, 32, 64);
          i32x4 bw;
          bw.x = (int)(hi ? rY0 : X0);
          bw.y = (int)(hi ? rY1 : X1);
          bw.z = (int)(hi ? Y0 : rX0);
          bw.w = (int)(hi ? Y1 : rX1);
          bf16x8 pf = __builtin_bit_cast(bf16x8, bw);
          __builtin_amdgcn_s_setprio(1);
#pragma unroll
          for (int t = 0; t < 2; ++t) {
            int row = t * 32 + l31;
            int col = (sub * 64 + c * 32 + hi * 16) ^ ((row & 7) << 4);
            bf16x8 vf = *(const bf16x8*)((const char*)&VT[cur][0] + row * 128 + col);
            ot[t] = MFMA32(vf, pf, ot[t]);
          }
          __builtin_amdgcn_s_setprio(0);
        }
      }
    }
    __syncthreads();                 // staged tile kt+1 complete; buf free
    cur ^= 1;
  }

  // ---- epilogue: normalize, per-wave LDS transpose, coalesced store ----
  uint32_t* Ow = (uint32_t*)((char*)&KT[0][0] + w * 4096);  // 4KB/wave, post-loop
  const float inv = 1.0f / l;
#pragma unroll
  for (int t = 0; t < 2; ++t)
#pragma unroll
    for (int g = 0; g < 4; ++g)
#pragma unroll
      for (int rp = 0; rp < 2; ++rp) {
        int r0 = 4 * g + 2 * rp;
        int ucol = rp + 4 * g + 2 * hi + 16 * t;   // (d>>1)
        Ow[l31 * 32 + (ucol ^ ((l31 & 7) << 2))] = cvtpk(ot[t][r0] * inv, ot[t][r0 + 1] * inv);
      }
  const int bb = bh / H_, h = bh % H_;
#pragma unroll
  for (int i = 0; i < 4; ++i) {
    int chunk = i * 64 + lane;           // 256 chunks of 16B = 32 rows x 128B
    int q = chunk >> 3, cc = chunk & 7;
    i32x4 v = *(const i32x4*)&Ow[q * 32 + ((cc * 4) ^ ((q & 7) << 2))];
    *(i32x4*)&Oa[((size_t)bb * S_ + q0 + q) * D_ + h * 64 + cc * 8] = v;
  }
}

// ---------------------------------------------------------------------------
extern "C" void kernel_launch(void* const* d_in, const int* in_sizes, int n_in,
                              void* d_out, int out_size, void* d_ws, size_t ws_size,
                              hipStream_t stream) {
  const float* x  = (const float*)d_in[0];
  const float* wq = (const float*)d_in[1];
  const float* bq = (const float*)d_in[2];
  const float* wk = (const float*)d_in[3];
  const float* bk = (const float*)d_in[4];
  const float* wv = (const float*)d_in[5];
  const float* bv = (const float*)d_in[6];
  const float* wo = (const float*)d_in[7];
  const float* bo = (const float*)d_in[8];

  const size_t XB = (size_t)M_ * D_;   // 6,291,456
  const size_t WB = (size_t)D_ * D_;   //   589,824
  ushort* xb    = (ushort*)d_ws;
  ushort* wqb   = xb + XB;
  ushort* wkb   = wqb + WB;
  ushort* wvb   = wkb + WB;
  ushort* wob   = wvb + WB;
  ushort* qb    = wob + WB;
  ushort* kbuf  = qb + XB;
  ushort* vtb   = kbuf + XB;
  ushort* attnb = vtb + XB;            // total ~67.6 MB

  cvt_f32_bf16<<<(int)(XB / 8 / 256), 256, 0, stream>>>(x, xb, (int)(XB / 8));
  cvtw_f32_bf16<<<dim3((int)(WB / 8 / 256), 4), 256, 0, stream>>>(
      wq, wk, wv, wo, wqb, wkb, wvb, wob, (int)(WB / 8));

  gemm_qkv<<<dim3(M_ / 128, 18), 256, 0, stream>>>(xb, wqb, wkb, wvb,
                                                   bq, bk, bv, qb, kbuf, vtb);
  attn_fwd4<<<dim3(B_ * H_, S_ / 128), 256, 0, stream>>>(qb, kbuf, vtb, attnb);
  gemm_out<<<dim3(M_ / 128, D_ / 128), 256, 0, stream>>>(attnb, wob, bo, (float*)d_out);
}

// Round 6
// 156.571 us; speedup vs baseline: 2.0737x; 1.1725x over previous
//
#include <hip/hip_runtime.h>
#include <hip/hip_bf16.h>
#include <cstdint>

// B=4, S=2048, D=768, H=12, DK=64. All fp32 in/out; bf16 MFMA compute inside.
static constexpr int B_ = 4, S_ = 2048, D_ = 768, H_ = 12, DK_ = 64;
static constexpr int M_ = B_ * S_;  // 8192 rows of x / attn

typedef short bf16x4 __attribute__((ext_vector_type(4)));
typedef short bf16x8 __attribute__((ext_vector_type(8)));   // 8 bf16 = 4 VGPRs
typedef float f32x4 __attribute__((ext_vector_type(4)));
typedef float f32x16 __attribute__((ext_vector_type(16)));
typedef int i32x4 __attribute__((ext_vector_type(4)));

#define MFMA16(a, b, c) __builtin_amdgcn_mfma_f32_16x16x32_bf16((a), (b), (c), 0, 0, 0)
#define MFMA32(a, b, c) __builtin_amdgcn_mfma_f32_32x32x16_bf16((a), (b), (c), 0, 0, 0)

__device__ inline ushort f2bf(float f) {
  uint32_t u = __float_as_uint(f);
  u += 0x7fffu + ((u >> 16) & 1u);  // round-nearest-even
  return (ushort)(u >> 16);
}
__device__ inline uint32_t pkbf(float a, float b) {
  return (uint32_t)f2bf(a) | ((uint32_t)f2bf(b) << 16);
}
// hardware packed f32->bf16 (RNE)
__device__ inline uint32_t cvtpk(float lo, float hi) {
  uint32_t r;
  asm("v_cvt_pk_bf16_f32 %0, %1, %2" : "=v"(r) : "v"(lo), "v"(hi));
  return r;
}
// async global->LDS, 16B per lane (LDS dest = wave-uniform base + lane*16)
__device__ inline void gload_lds16(const void* g, void* l) {
  __builtin_amdgcn_global_load_lds((const __attribute__((address_space(1))) void*)g,
                                   (__attribute__((address_space(3))) void*)l, 16, 0, 0);
}

// ---------------- fp32 -> bf16 convert (8 elems/thread, 16B store) ----------
__global__ void cvt_f32_bf16(const float* __restrict__ in, ushort* __restrict__ out, int n8) {
  int i = blockIdx.x * 256 + threadIdx.x;
  if (i >= n8) return;
  const float4* p = (const float4*)in;
  float4 v0 = p[2 * i], v1 = p[2 * i + 1];
  ((uint4*)out)[i] = make_uint4(pkbf(v0.x, v0.y), pkbf(v0.z, v0.w),
                                pkbf(v1.x, v1.y), pkbf(v1.z, v1.w));
}

// 4 weight matrices in one launch (blockIdx.y selects)
__global__ void cvtw_f32_bf16(const float* __restrict__ w0, const float* __restrict__ w1,
                              const float* __restrict__ w2, const float* __restrict__ w3,
                              ushort* __restrict__ o0, ushort* __restrict__ o1,
                              ushort* __restrict__ o2, ushort* __restrict__ o3, int n8) {
  const float* in;
  ushort* out;
  switch (blockIdx.y) {
    case 0: in = w0; out = o0; break;
    case 1: in = w1; out = o1; break;
    case 2: in = w2; out = o2; break;
    default: in = w3; out = o3; break;
  }
  int i = blockIdx.x * 256 + threadIdx.x;
  if (i >= n8) return;
  const float4* p = (const float4*)in;
  float4 v0 = p[2 * i], v1 = p[2 * i + 1];
  ((uint4*)out)[i] = make_uint4(pkbf(v0.x, v0.y), pkbf(v0.z, v0.w),
                                pkbf(v1.x, v1.y), pkbf(v1.z, v1.w));
}

// ---------------- fused QKV GEMM: one launch, N = 3*768 --------------------
__global__ __launch_bounds__(256) void gemm_qkv(const ushort* __restrict__ A,
                                                const ushort* __restrict__ Wq,
                                                const ushort* __restrict__ Wk,
                                                const ushort* __restrict__ Wv,
                                                const float* __restrict__ bqp,
                                                const float* __restrict__ bkp,
                                                const float* __restrict__ bvp,
                                                ushort* __restrict__ Qo,
                                                ushort* __restrict__ Ko,
                                                ushort* __restrict__ Vo) {
  constexpr int K = D_;   // 768
  constexpr int BK = 32;
  __shared__ ushort As[128 * BK];
  __shared__ ushort Bs[128 * BK];

  const int wsel = blockIdx.y / 6;
  const int bn = (blockIdx.y % 6) * 128;
  const ushort* Bw = wsel == 0 ? Wq : wsel == 1 ? Wk : Wv;
  const float* bias = wsel == 0 ? bqp : wsel == 1 ? bkp : bvp;
  ushort* outp = wsel == 0 ? Qo : wsel == 1 ? Ko : Vo;

  const int tid = threadIdx.x;
  const int lane = tid & 63, w = tid >> 6;
  const int wr = w >> 1, wc = w & 1;
  const int l15 = lane & 15, l4 = lane >> 4;
  const int bm = blockIdx.x * 128;

  f32x4 acc[4][4] = {};

  for (int k0 = 0; k0 < K; k0 += BK) {
    __syncthreads();
#pragma unroll
    for (int i = 0; i < 2; ++i) {
      int e = (i * 256 + tid) * 8;
      int r = e >> 5, c = e & 31;
      gload_lds16(&A[(size_t)(bm + r) * K + k0 + c], &As[e]);
      gload_lds16(&Bw[(size_t)(bn + r) * K + k0 + c], &Bs[e]);
    }
    __syncthreads();
    bf16x8 a[4], b[4];
#pragma unroll
    for (int mi = 0; mi < 4; ++mi)
      a[mi] = *(const bf16x8*)&As[(wr * 64 + mi * 16 + l15) * BK + l4 * 8];
#pragma unroll
    for (int ni = 0; ni < 4; ++ni)
      b[ni] = *(const bf16x8*)&Bs[(wc * 64 + ni * 16 + l15) * BK + l4 * 8];
    __builtin_amdgcn_s_setprio(1);
#pragma unroll
    for (int mi = 0; mi < 4; ++mi)
#pragma unroll
      for (int ni = 0; ni < 4; ++ni)
        acc[mi][ni] = MFMA16(a[mi], b[ni], acc[mi][ni]);
    __builtin_amdgcn_s_setprio(0);
  }

#pragma unroll
  for (int mi = 0; mi < 4; ++mi) {
#pragma unroll
    for (int ni = 0; ni < 4; ++ni) {
      int col = bn + wc * 64 + ni * 16 + l15;
      float bv = bias[col];
#pragma unroll
      for (int r = 0; r < 4; ++r) {
        int row = bm + wr * 64 + mi * 16 + l4 * 4 + r;
        float v = acc[mi][ni][r] + bv;
        int bb = row >> 11, s = row & 2047;
        int h = col >> 6, dk = col & 63;
        if (wsel < 2)
          outp[(((bb * H_ + h) * S_ + s) << 6) + dk] = f2bf(v);
        else
          outp[(((bb * H_ + h) << 6) + dk) * S_ + s] = f2bf(v);
      }
    }
  }
}

// ---------------- output GEMM: 64x128 tiles (768 blocks), fp32 out ----------
__global__ __launch_bounds__(256) void gemm_out(const ushort* __restrict__ A,
                                                const ushort* __restrict__ Bw,
                                                const float* __restrict__ bias,
                                                float* __restrict__ outp) {
  constexpr int K = D_;
  constexpr int BK = 32;
  __shared__ ushort As[64 * BK];
  __shared__ ushort Bs[128 * BK];

  const int tid = threadIdx.x;
  const int lane = tid & 63, w = tid >> 6;
  const int wr = w >> 1, wc = w & 1;           // wave tile: 32 rows x 64 cols
  const int l15 = lane & 15, l4 = lane >> 4;
  const int bm = blockIdx.x * 64, bn = blockIdx.y * 128;

  f32x4 acc[2][4] = {};

  for (int k0 = 0; k0 < K; k0 += BK) {
    __syncthreads();
    {
      int e = tid * 8;                          // A: 64x32 = 2048 elems, 1 round
      int r = e >> 5, c = e & 31;
      gload_lds16(&A[(size_t)(bm + r) * K + k0 + c], &As[e]);
    }
#pragma unroll
    for (int i = 0; i < 2; ++i) {               // B: 128x32 = 4096 elems, 2 rounds
      int e = (i * 256 + tid) * 8;
      int r = e >> 5, c = e & 31;
      gload_lds16(&Bw[(size_t)(bn + r) * K + k0 + c], &Bs[e]);
    }
    __syncthreads();
    bf16x8 a[2], b[4];
#pragma unroll
    for (int mi = 0; mi < 2; ++mi)
      a[mi] = *(const bf16x8*)&As[(wr * 32 + mi * 16 + l15) * BK + l4 * 8];
#pragma unroll
    for (int ni = 0; ni < 4; ++ni)
      b[ni] = *(const bf16x8*)&Bs[(wc * 64 + ni * 16 + l15) * BK + l4 * 8];
    __builtin_amdgcn_s_setprio(1);
#pragma unroll
    for (int mi = 0; mi < 2; ++mi)
#pragma unroll
      for (int ni = 0; ni < 4; ++ni)
        acc[mi][ni] = MFMA16(a[mi], b[ni], acc[mi][ni]);
    __builtin_amdgcn_s_setprio(0);
  }

#pragma unroll
  for (int mi = 0; mi < 2; ++mi)
#pragma unroll
    for (int ni = 0; ni < 4; ++ni) {
      int col = bn + wc * 64 + ni * 16 + l15;
      float bv = bias[col];
#pragma unroll
      for (int r = 0; r < 4; ++r) {
        int row = bm + wr * 32 + mi * 16 + l4 * 4 + r;
        outp[(size_t)row * D_ + col] = acc[mi][ni][r] + bv;
      }
    }
}

// ---------------- causal flash attention: 8 waves, sub-tile KV-split --------
// grid (B*H, S/128), 512 threads = 8 waves = 4 q-pairs x 2 key-splits.
// pair = w>>1 owns q-rows [qb+pair*32, +32); sp = w&1 handles key sub-tile
// sp of each staged 64-key tile (keys k0+sp*32..+31). Both splits walk the
// SAME staged KV stream (shared LDS, lockstep barriers); per-pair (m,l,O)
// merge at the end (fwd3-verified math). Zero-shuffle PV: the MFMA k-slot ->
// key mapping is permuted so each lane feeds its own St registers; V^T is
// read with two b64 loads at the matching columns (sum over keys commutes).
__global__ __launch_bounds__(512) void attn_fwd5(const ushort* __restrict__ Q,
                                                 const ushort* __restrict__ Kg,
                                                 const ushort* __restrict__ Vt,
                                                 ushort* __restrict__ Oa) {
  __shared__ ushort KVb[2][2][64 * 64];       // [kind K/V][buf][tile] = 32KB
  __shared__ float Ml[4][32], Ll[4][32];

  const int bh = blockIdx.x;
  const int w = threadIdx.x >> 6, lane = threadIdx.x & 63;
  const int l31 = lane & 31, hi = lane >> 5;
  const int pair = w >> 1, sp = w & 1;
  const int qtb = gridDim.y - 1 - blockIdx.y;      // heavy blocks first
  const int qb = qtb * 128;
  const int q0 = qb + pair * 32;

  const ushort* Qb = Q + (size_t)bh * (S_ * DK_);
  const char* Kc = (const char*)(Kg + (size_t)bh * (S_ * DK_));
  const char* Vc = (const char*)(Vt + (size_t)bh * (DK_ * S_));
  char* kKT = (char*)&KVb[0][0][0];
  char* kVT = (char*)&KVb[1][0][0];

  // Q B-fragments: col=lane&31=q, k elem j -> d = kc*16 + hi*8 + j
  bf16x8 qf[4];
#pragma unroll
  for (int kc = 0; kc < 4; ++kc)
    qf[kc] = *(const bf16x8*)&Qb[(q0 + l31) * 64 + kc * 16 + hi * 8];

  f32x16 ot[2] = {};                 // O^T: row d=(r&3)+8*(r>>2)+4*hi+32t, col q=l31
  float m = -__builtin_inff(), l = 0.f;
  const float C = 0.125f * 1.4426950408889634f;  // 1/sqrt(64) * log2(e)
  const float THR = 8.0f / C;

  // cooperative stage of 64-key tile kt (8 waves x 1KB each for K, then V)
  auto stage = [&](int buf, int kt) {
    const int k0 = kt * 64;
    int obase = w * 1024;
    int o = obase + lane * 16;
    int mk = ((o >> 7) & 7) << 4;                  // XOR swizzle (rule #21)
    gload_lds16(Kc + (size_t)k0 * 128 + (o ^ mk), kKT + buf * 8192 + obase);
    int d = o >> 7, colb = (o & 127) ^ mk;
    gload_lds16(Vc + (size_t)d * 4096 + (size_t)k0 * 2 + colb, kVT + buf * 8192 + obase);
  };

  const int nkt = qb / 64 + 2;       // walk keys [0, qb+128)
  int cur = 0;
  stage(0, 0);
  __syncthreads();

  for (int kt = 0; kt < nkt; ++kt) {
    if (kt + 1 < nkt) stage(cur ^ 1, kt + 1);
    const int ks = kt * 64 + sp * 32;
    if (ks <= q0 + 31) {             // wave-uniform
      const char* KTc = kKT + cur * 8192;
      const char* VTc = kVT + cur * 8192;
      // --- St = K Q^T (4 MFMAs), K frags from swizzled LDS ---
      f32x16 st = {};
      __builtin_amdgcn_s_setprio(1);
#pragma unroll
      for (int kc = 0; kc < 4; ++kc) {
        int row = sp * 32 + l31;
        int col = (kc * 32 + hi * 16) ^ ((row & 7) << 4);
        bf16x8 kf = *(const bf16x8*)(KTc + row * 128 + col);
        st = MFMA32(kf, qf[kc], st);
      }
      __builtin_amdgcn_s_setprio(0);
      // --- causal mask (partial tile only) ---
      if (ks + 31 > q0) {
#pragma unroll
        for (int r = 0; r < 16; ++r) {
          int kr = ks + (r & 3) + 8 * (r >> 2) + 4 * hi;
          if (kr > q0 + l31) st[r] = -__builtin_inff();
        }
      }
      // --- row max: tree + 1 shfl ---
      float mx[8];
#pragma unroll
      for (int i = 0; i < 8; ++i) mx[i] = fmaxf(st[i], st[i + 8]);
#pragma unroll
      for (int i = 0; i < 4; ++i) mx[i] = fmaxf(mx[i], mx[i + 4]);
      float pm = fmaxf(fmaxf(mx[0], mx[1]), fmaxf(mx[2], mx[3]));
      pm = fmaxf(pm, __shfl_xor(pm, 32, 64));
      // --- defer-max rescale ---
      if (!__all(pm <= m + THR)) {
        float mn = fmaxf(m, pm);
        float al = exp2f((m - mn) * C);
        m = mn;
        l *= al;
#pragma unroll
        for (int t = 0; t < 2; ++t)
#pragma unroll
          for (int r = 0; r < 16; ++r) ot[t][r] *= al;
      }
      // --- p = exp2(s*C - m*C); tree row-sum ---
      const float mc = m * C;
#pragma unroll
      for (int r = 0; r < 16; ++r) st[r] = exp2f(fmaf(st[r], C, -mc));
      float sx[8];
#pragma unroll
      for (int i = 0; i < 8; ++i) sx[i] = st[i] + st[i + 8];
#pragma unroll
      for (int i = 0; i < 4; ++i) sx[i] = sx[i] + sx[i + 4];
      float rs = (sx[0] + sx[1]) + (sx[2] + sx[3]);
      rs += __shfl_xor(rs, 32, 64);
      l += rs;
      // --- zero-shuffle PV: B-frag = own St regs in order; V^T via 2x b64 ---
      // lane's st keys (c-chunk): {16c+4hi+0..3, 16c+8+4hi+0..3} == MFMA k-slots
#pragma unroll
      for (int c = 0; c < 2; ++c) {
        i32x4 bw;
        bw.x = (int)cvtpk(st[8 * c + 0], st[8 * c + 1]);
        bw.y = (int)cvtpk(st[8 * c + 2], st[8 * c + 3]);
        bw.z = (int)cvtpk(st[8 * c + 4], st[8 * c + 5]);
        bw.w = (int)cvtpk(st[8 * c + 6], st[8 * c + 7]);
        bf16x8 pf = __builtin_bit_cast(bf16x8, bw);
        __builtin_amdgcn_s_setprio(1);
#pragma unroll
        for (int t = 0; t < 2; ++t) {
          int row = t * 32 + l31;
          int swz = (row & 7) << 4;
          int colA = sp * 64 + c * 32 + hi * 8;       // keys 16c+4hi..+3 (bytes)
          bf16x4 vlo = *(const bf16x4*)(VTc + row * 128 + (colA ^ swz));
          bf16x4 vhi = *(const bf16x4*)(VTc + row * 128 + ((colA + 16) ^ swz));
          bf16x8 vf = __builtin_shufflevector(vlo, vhi, 0, 1, 2, 3, 4, 5, 6, 7);
          ot[t] = MFMA32(vf, pf, ot[t]);
        }
        __builtin_amdgcn_s_setprio(0);
      }
    }
    __syncthreads();                 // staged tile kt+1 complete; buf free
    cur ^= 1;
  }

  // ---- merge the two key-splits per pair (KV LDS reused as scratch) ----
  float* Om = (float*)&KVb[0][0][0];            // [4][64][32] f32 = 32KB
  if (sp == 0) {
#pragma unroll
    for (int t = 0; t < 2; ++t)
#pragma unroll
      for (int r = 0; r < 16; ++r) {
        int d = (r & 3) + 8 * (r >> 2) + 4 * hi + 32 * t;
        Om[(pair * 64 + d) * 32 + l31] = ot[t][r];
      }
    if (hi == 0) { Ml[pair][l31] = m; Ll[pair][l31] = l; }
  }
  __syncthreads();
  if (sp == 1) {
    float m0 = Ml[pair][l31], l0 = Ll[pair][l31];
    float M = fmaxf(m, m0);
    float a1 = exp2f((m - M) * C), a0 = exp2f((m0 - M) * C);
    float inv = 1.0f / (a1 * l + a0 * l0);
    a1 *= inv; a0 *= inv;
#pragma unroll
    for (int t = 0; t < 2; ++t)
#pragma unroll
      for (int r = 0; r < 16; ++r) {
        int d = (r & 3) + 8 * (r >> 2) + 4 * hi + 32 * t;
        ot[t][r] = a1 * ot[t][r] + a0 * Om[(pair * 64 + d) * 32 + l31];
      }
    // transpose staging reuses this pair's Om region (same-wave RAW via lgkmcnt)
    uint32_t* Ow = (uint32_t*)&Om[pair * 64 * 32];
#pragma unroll
    for (int t = 0; t < 2; ++t)
#pragma unroll
      for (int g = 0; g < 4; ++g)
#pragma unroll
        for (int rp = 0; rp < 2; ++rp) {
          int r0 = 4 * g + 2 * rp;
          int ucol = rp + 4 * g + 2 * hi + 16 * t;   // (d>>1)
          Ow[l31 * 32 + (ucol ^ ((l31 & 7) << 2))] = cvtpk(ot[t][r0], ot[t][r0 + 1]);
        }
    const int bb = bh / H_, h = bh % H_;
#pragma unroll
    for (int i = 0; i < 4; ++i) {
      int chunk = i * 64 + lane;           // 256 chunks of 16B = 32 rows x 128B
      int q = chunk >> 3, cc = chunk & 7;
      i32x4 v = *(const i32x4*)&Ow[q * 32 + ((cc * 4) ^ ((q & 7) << 2))];
      *(i32x4*)&Oa[((size_t)bb * S_ + q0 + q) * D_ + h * 64 + cc * 8] = v;
    }
  }
}

// ---------------------------------------------------------------------------
extern "C" void kernel_launch(void* const* d_in, const int* in_sizes, int n_in,
                              void* d_out, int out_size, void* d_ws, size_t ws_size,
                              hipStream_t stream) {
  const float* x  = (const float*)d_in[0];
  const float* wq = (const float*)d_in[1];
  const float* bq = (const float*)d_in[2];
  const float* wk = (const float*)d_in[3];
  const float* bk = (const float*)d_in[4];
  const float* wv = (const float*)d_in[5];
  const float* bv = (const float*)d_in[6];
  const float* wo = (const float*)d_in[7];
  const float* bo = (const float*)d_in[8];

  const size_t XB = (size_t)M_ * D_;   // 6,291,456
  const size_t WB = (size_t)D_ * D_;   //   589,824
  ushort* xb    = (ushort*)d_ws;
  ushort* wqb   = xb + XB;
  ushort* wkb   = wqb + WB;
  ushort* wvb   = wkb + WB;
  ushort* wob   = wvb + WB;
  ushort* qb    = wob + WB;
  ushort* kbuf  = qb + XB;
  ushort* vtb   = kbuf + XB;
  ushort* attnb = vtb + XB;            // total ~67.6 MB

  cvt_f32_bf16<<<(int)(XB / 8 / 256), 256, 0, stream>>>(x, xb, (int)(XB / 8));
  cvtw_f32_bf16<<<dim3((int)(WB / 8 / 256), 4), 256, 0, stream>>>(
      wq, wk, wv, wo, wqb, wkb, wvb, wob, (int)(WB / 8));

  gemm_qkv<<<dim3(M_ / 128, 18), 256, 0, stream>>>(xb, wqb, wkb, wvb,
                                                   bq, bk, bv, qb, kbuf, vtb);
  attn_fwd5<<<dim3(B_ * H_, S_ / 128), 512, 0, stream>>>(qb, kbuf, vtb, attnb);
  gemm_out<<<dim3(M_ / 64, D_ / 128), 256, 0, stream>>>(attnb, wob, bo, (float*)d_out);
}

// Round 7
// 144.667 us; speedup vs baseline: 2.2443x; 1.0823x over previous
//
#include <hip/hip_runtime.h>
#include <hip/hip_bf16.h>
#include <cstdint>

// B=4, S=2048, D=768, H=12, DK=64. All fp32 in/out; bf16 MFMA compute inside.
static constexpr int B_ = 4, S_ = 2048, D_ = 768, H_ = 12, DK_ = 64;
static constexpr int M_ = B_ * S_;  // 8192 rows of x / attn

typedef short bf16x4 __attribute__((ext_vector_type(4)));
typedef short bf16x8 __attribute__((ext_vector_type(8)));   // 8 bf16 = 4 VGPRs
typedef float f32x4 __attribute__((ext_vector_type(4)));
typedef float f32x16 __attribute__((ext_vector_type(16)));
typedef int i32x4 __attribute__((ext_vector_type(4)));

#define MFMA16(a, b, c) __builtin_amdgcn_mfma_f32_16x16x32_bf16((a), (b), (c), 0, 0, 0)
#define MFMA32(a, b, c) __builtin_amdgcn_mfma_f32_32x32x16_bf16((a), (b), (c), 0, 0, 0)

__device__ inline ushort f2bf(float f) {
  uint32_t u = __float_as_uint(f);
  u += 0x7fffu + ((u >> 16) & 1u);  // round-nearest-even
  return (ushort)(u >> 16);
}
__device__ inline uint32_t pkbf(float a, float b) {
  return (uint32_t)f2bf(a) | ((uint32_t)f2bf(b) << 16);
}
// hardware packed f32->bf16 (RNE)
__device__ inline uint32_t cvtpk(float lo, float hi) {
  uint32_t r;
  asm("v_cvt_pk_bf16_f32 %0, %1, %2" : "=v"(r) : "v"(lo), "v"(hi));
  return r;
}
// async global->LDS, 16B per lane (LDS dest = wave-uniform base + lane*16)
__device__ inline void gload_lds16(const void* g, void* l) {
  __builtin_amdgcn_global_load_lds((const __attribute__((address_space(1))) void*)g,
                                   (__attribute__((address_space(3))) void*)l, 16, 0, 0);
}

// ---------------- fp32 -> bf16 convert (8 elems/thread, 16B store) ----------
__global__ void cvt_f32_bf16(const float* __restrict__ in, ushort* __restrict__ out, int n8) {
  int i = blockIdx.x * 256 + threadIdx.x;
  if (i >= n8) return;
  const float4* p = (const float4*)in;
  float4 v0 = p[2 * i], v1 = p[2 * i + 1];
  ((uint4*)out)[i] = make_uint4(pkbf(v0.x, v0.y), pkbf(v0.z, v0.w),
                                pkbf(v1.x, v1.y), pkbf(v1.z, v1.w));
}

// 4 weight matrices in one launch (blockIdx.y selects)
__global__ void cvtw_f32_bf16(const float* __restrict__ w0, const float* __restrict__ w1,
                              const float* __restrict__ w2, const float* __restrict__ w3,
                              ushort* __restrict__ o0, ushort* __restrict__ o1,
                              ushort* __restrict__ o2, ushort* __restrict__ o3, int n8) {
  const float* in;
  ushort* out;
  switch (blockIdx.y) {
    case 0: in = w0; out = o0; break;
    case 1: in = w1; out = o1; break;
    case 2: in = w2; out = o2; break;
    default: in = w3; out = o3; break;
  }
  int i = blockIdx.x * 256 + threadIdx.x;
  if (i >= n8) return;
  const float4* p = (const float4*)in;
  float4 v0 = p[2 * i], v1 = p[2 * i + 1];
  ((uint4*)out)[i] = make_uint4(pkbf(v0.x, v0.y), pkbf(v0.z, v0.w),
                                pkbf(v1.x, v1.y), pkbf(v1.z, v1.w));
}

// ---------------- fused QKV GEMM: 2-phase double-buffered LDS ---------------
// blockIdx.y in [0,18): wsel = y/6 selects {Wq->Q, Wk->K, Wv->V^T}.
// T3-minimum: STAGE(next) issued BEFORE compute(cur); single barrier per
// K-step so the vmcnt(0) drain lands after ~200cyc of ds_read+MFMA cover.
__global__ __launch_bounds__(256) void gemm_qkv(const ushort* __restrict__ A,
                                                const ushort* __restrict__ Wq,
                                                const ushort* __restrict__ Wk,
                                                const ushort* __restrict__ Wv,
                                                const float* __restrict__ bqp,
                                                const float* __restrict__ bkp,
                                                const float* __restrict__ bvp,
                                                ushort* __restrict__ Qo,
                                                ushort* __restrict__ Ko,
                                                ushort* __restrict__ Vo) {
  constexpr int K = D_;   // 768
  constexpr int BK = 32;
  constexpr int NT = K / BK;  // 24
  __shared__ ushort As[2][128 * BK];
  __shared__ ushort Bs[2][128 * BK];

  const int wsel = blockIdx.y / 6;
  const int bn = (blockIdx.y % 6) * 128;
  const ushort* Bw = wsel == 0 ? Wq : wsel == 1 ? Wk : Wv;
  const float* bias = wsel == 0 ? bqp : wsel == 1 ? bkp : bvp;
  ushort* outp = wsel == 0 ? Qo : wsel == 1 ? Ko : Vo;

  const int tid = threadIdx.x;
  const int lane = tid & 63, w = tid >> 6;
  const int wr = w >> 1, wc = w & 1;
  const int l15 = lane & 15, l4 = lane >> 4;
  const int bm = blockIdx.x * 128;

  f32x4 acc[4][4] = {};

  auto stage = [&](int buf, int k0) {
#pragma unroll
    for (int i = 0; i < 2; ++i) {
      int e = (i * 256 + tid) * 8;
      int r = e >> 5, c = e & 31;
      gload_lds16(&A[(size_t)(bm + r) * K + k0 + c], &As[buf][e]);
      gload_lds16(&Bw[(size_t)(bn + r) * K + k0 + c], &Bs[buf][e]);
    }
  };

  stage(0, 0);
  __syncthreads();           // buf0 ready
  int cur = 0;
  for (int t = 0; t < NT; ++t) {
    if (t + 1 < NT) stage(cur ^ 1, (t + 1) * BK);   // prefetch next tile
    bf16x8 a[4], b[4];
#pragma unroll
    for (int mi = 0; mi < 4; ++mi)
      a[mi] = *(const bf16x8*)&As[cur][(wr * 64 + mi * 16 + l15) * BK + l4 * 8];
#pragma unroll
    for (int ni = 0; ni < 4; ++ni)
      b[ni] = *(const bf16x8*)&Bs[cur][(wc * 64 + ni * 16 + l15) * BK + l4 * 8];
    __builtin_amdgcn_s_setprio(1);
#pragma unroll
    for (int mi = 0; mi < 4; ++mi)
#pragma unroll
      for (int ni = 0; ni < 4; ++ni)
        acc[mi][ni] = MFMA16(a[mi], b[ni], acc[mi][ni]);
    __builtin_amdgcn_s_setprio(0);
    __syncthreads();         // next-tile loads landed; cur free for overwrite
    cur ^= 1;
  }

#pragma unroll
  for (int mi = 0; mi < 4; ++mi) {
#pragma unroll
    for (int ni = 0; ni < 4; ++ni) {
      int col = bn + wc * 64 + ni * 16 + l15;
      float bv = bias[col];
#pragma unroll
      for (int r = 0; r < 4; ++r) {
        int row = bm + wr * 64 + mi * 16 + l4 * 4 + r;
        float v = acc[mi][ni][r] + bv;
        int bb = row >> 11, s = row & 2047;
        int h = col >> 6, dk = col & 63;
        if (wsel < 2)
          outp[(((bb * H_ + h) * S_ + s) << 6) + dk] = f2bf(v);
        else
          outp[(((bb * H_ + h) << 6) + dk) * S_ + s] = f2bf(v);
      }
    }
  }
}

// ---------------- output GEMM: 64x128 tiles, 2-phase dbuf, fp32 out ---------
__global__ __launch_bounds__(256) void gemm_out(const ushort* __restrict__ A,
                                                const ushort* __restrict__ Bw,
                                                const float* __restrict__ bias,
                                                float* __restrict__ outp) {
  constexpr int K = D_;
  constexpr int BK = 32;
  constexpr int NT = K / BK;
  __shared__ ushort As[2][64 * BK];
  __shared__ ushort Bs[2][128 * BK];

  const int tid = threadIdx.x;
  const int lane = tid & 63, w = tid >> 6;
  const int wr = w >> 1, wc = w & 1;           // wave tile: 32 rows x 64 cols
  const int l15 = lane & 15, l4 = lane >> 4;
  const int bm = blockIdx.x * 64, bn = blockIdx.y * 128;

  f32x4 acc[2][4] = {};

  auto stage = [&](int buf, int k0) {
    {
      int e = tid * 8;                          // A: 64x32 = 2048 elems
      int r = e >> 5, c = e & 31;
      gload_lds16(&A[(size_t)(bm + r) * K + k0 + c], &As[buf][e]);
    }
#pragma unroll
    for (int i = 0; i < 2; ++i) {               // B: 128x32 = 4096 elems
      int e = (i * 256 + tid) * 8;
      int r = e >> 5, c = e & 31;
      gload_lds16(&Bw[(size_t)(bn + r) * K + k0 + c], &Bs[buf][e]);
    }
  };

  stage(0, 0);
  __syncthreads();
  int cur = 0;
  for (int t = 0; t < NT; ++t) {
    if (t + 1 < NT) stage(cur ^ 1, (t + 1) * BK);
    bf16x8 a[2], b[4];
#pragma unroll
    for (int mi = 0; mi < 2; ++mi)
      a[mi] = *(const bf16x8*)&As[cur][(wr * 32 + mi * 16 + l15) * BK + l4 * 8];
#pragma unroll
    for (int ni = 0; ni < 4; ++ni)
      b[ni] = *(const bf16x8*)&Bs[cur][(wc * 64 + ni * 16 + l15) * BK + l4 * 8];
    __builtin_amdgcn_s_setprio(1);
#pragma unroll
    for (int mi = 0; mi < 2; ++mi)
#pragma unroll
      for (int ni = 0; ni < 4; ++ni)
        acc[mi][ni] = MFMA16(a[mi], b[ni], acc[mi][ni]);
    __builtin_amdgcn_s_setprio(0);
    __syncthreads();
    cur ^= 1;
  }

#pragma unroll
  for (int mi = 0; mi < 2; ++mi)
#pragma unroll
    for (int ni = 0; ni < 4; ++ni) {
      int col = bn + wc * 64 + ni * 16 + l15;
      float bv = bias[col];
#pragma unroll
      for (int r = 0; r < 4; ++r) {
        int row = bm + wr * 32 + mi * 16 + l4 * 4 + r;
        outp[(size_t)row * D_ + col] = acc[mi][ni][r] + bv;
      }
    }
}

// ---------------- causal flash attention: 8 waves, sub-tile KV-split --------
// (unchanged from round 5 — attribution: this round only changes the GEMMs)
__global__ __launch_bounds__(512) void attn_fwd5(const ushort* __restrict__ Q,
                                                 const ushort* __restrict__ Kg,
                                                 const ushort* __restrict__ Vt,
                                                 ushort* __restrict__ Oa) {
  __shared__ ushort KVb[2][2][64 * 64];       // [kind K/V][buf][tile] = 32KB
  __shared__ float Ml[4][32], Ll[4][32];

  const int bh = blockIdx.x;
  const int w = threadIdx.x >> 6, lane = threadIdx.x & 63;
  const int l31 = lane & 31, hi = lane >> 5;
  const int pair = w >> 1, sp = w & 1;
  const int qtb = gridDim.y - 1 - blockIdx.y;      // heavy blocks first
  const int qb = qtb * 128;
  const int q0 = qb + pair * 32;

  const ushort* Qb = Q + (size_t)bh * (S_ * DK_);
  const char* Kc = (const char*)(Kg + (size_t)bh * (S_ * DK_));
  const char* Vc = (const char*)(Vt + (size_t)bh * (DK_ * S_));
  char* kKT = (char*)&KVb[0][0][0];
  char* kVT = (char*)&KVb[1][0][0];

  bf16x8 qf[4];
#pragma unroll
  for (int kc = 0; kc < 4; ++kc)
    qf[kc] = *(const bf16x8*)&Qb[(q0 + l31) * 64 + kc * 16 + hi * 8];

  f32x16 ot[2] = {};                 // O^T: row d=(r&3)+8*(r>>2)+4*hi+32t, col q=l31
  float m = -__builtin_inff(), l = 0.f;
  const float C = 0.125f * 1.4426950408889634f;  // 1/sqrt(64) * log2(e)
  const float THR = 8.0f / C;

  auto stage = [&](int buf, int kt) {
    const int k0 = kt * 64;
    int obase = w * 1024;
    int o = obase + lane * 16;
    int mk = ((o >> 7) & 7) << 4;                  // XOR swizzle (rule #21)
    gload_lds16(Kc + (size_t)k0 * 128 + (o ^ mk), kKT + buf * 8192 + obase);
    int d = o >> 7, colb = (o & 127) ^ mk;
    gload_lds16(Vc + (size_t)d * 4096 + (size_t)k0 * 2 + colb, kVT + buf * 8192 + obase);
  };

  const int nkt = qb / 64 + 2;       // walk keys [0, qb+128)
  int cur = 0;
  stage(0, 0);
  __syncthreads();

  for (int kt = 0; kt < nkt; ++kt) {
    if (kt + 1 < nkt) stage(cur ^ 1, kt + 1);
    const int ks = kt * 64 + sp * 32;
    if (ks <= q0 + 31) {             // wave-uniform
      const char* KTc = kKT + cur * 8192;
      const char* VTc = kVT + cur * 8192;
      f32x16 st = {};
      __builtin_amdgcn_s_setprio(1);
#pragma unroll
      for (int kc = 0; kc < 4; ++kc) {
        int row = sp * 32 + l31;
        int col = (kc * 32 + hi * 16) ^ ((row & 7) << 4);
        bf16x8 kf = *(const bf16x8*)(KTc + row * 128 + col);
        st = MFMA32(kf, qf[kc], st);
      }
      __builtin_amdgcn_s_setprio(0);
      if (ks + 31 > q0) {
#pragma unroll
        for (int r = 0; r < 16; ++r) {
          int kr = ks + (r & 3) + 8 * (r >> 2) + 4 * hi;
          if (kr > q0 + l31) st[r] = -__builtin_inff();
        }
      }
      float mx[8];
#pragma unroll
      for (int i = 0; i < 8; ++i) mx[i] = fmaxf(st[i], st[i + 8]);
#pragma unroll
      for (int i = 0; i < 4; ++i) mx[i] = fmaxf(mx[i], mx[i + 4]);
      float pm = fmaxf(fmaxf(mx[0], mx[1]), fmaxf(mx[2], mx[3]));
      pm = fmaxf(pm, __shfl_xor(pm, 32, 64));
      if (!__all(pm <= m + THR)) {
        float mn = fmaxf(m, pm);
        float al = exp2f((m - mn) * C);
        m = mn;
        l *= al;
#pragma unroll
        for (int t = 0; t < 2; ++t)
#pragma unroll
          for (int r = 0; r < 16; ++r) ot[t][r] *= al;
      }
      const float mc = m * C;
#pragma unroll
      for (int r = 0; r < 16; ++r) st[r] = exp2f(fmaf(st[r], C, -mc));
      float sx[8];
#pragma unroll
      for (int i = 0; i < 8; ++i) sx[i] = st[i] + st[i + 8];
#pragma unroll
      for (int i = 0; i < 4; ++i) sx[i] = sx[i] + sx[i + 4];
      float rs = (sx[0] + sx[1]) + (sx[2] + sx[3]);
      rs += __shfl_xor(rs, 32, 64);
      l += rs;
      // zero-shuffle PV: B-frag = own St regs in order; V^T via 2x b64
#pragma unroll
      for (int c = 0; c < 2; ++c) {
        i32x4 bw;
        bw.x = (int)cvtpk(st[8 * c + 0], st[8 * c + 1]);
        bw.y = (int)cvtpk(st[8 * c + 2], st[8 * c + 3]);
        bw.z = (int)cvtpk(st[8 * c + 4], st[8 * c + 5]);
        bw.w = (int)cvtpk(st[8 * c + 6], st[8 * c + 7]);
        bf16x8 pf = __builtin_bit_cast(bf16x8, bw);
        __builtin_amdgcn_s_setprio(1);
#pragma unroll
        for (int t = 0; t < 2; ++t) {
          int row = t * 32 + l31;
          int swz = (row & 7) << 4;
          int colA = sp * 64 + c * 32 + hi * 8;
          bf16x4 vlo = *(const bf16x4*)(VTc + row * 128 + (colA ^ swz));
          bf16x4 vhi = *(const bf16x4*)(VTc + row * 128 + ((colA + 16) ^ swz));
          bf16x8 vf = __builtin_shufflevector(vlo, vhi, 0, 1, 2, 3, 4, 5, 6, 7);
          ot[t] = MFMA32(vf, pf, ot[t]);
        }
        __builtin_amdgcn_s_setprio(0);
      }
    }
    __syncthreads();
    cur ^= 1;
  }

  // ---- merge the two key-splits per pair (KV LDS reused as scratch) ----
  float* Om = (float*)&KVb[0][0][0];            // [4][64][32] f32 = 32KB
  if (sp == 0) {
#pragma unroll
    for (int t = 0; t < 2; ++t)
#pragma unroll
      for (int r = 0; r < 16; ++r) {
        int d = (r & 3) + 8 * (r >> 2) + 4 * hi + 32 * t;
        Om[(pair * 64 + d) * 32 + l31] = ot[t][r];
      }
    if (hi == 0) { Ml[pair][l31] = m; Ll[pair][l31] = l; }
  }
  __syncthreads();
  if (sp == 1) {
    float m0 = Ml[pair][l31], l0 = Ll[pair][l31];
    float M = fmaxf(m, m0);
    float a1 = exp2f((m - M) * C), a0 = exp2f((m0 - M) * C);
    float inv = 1.0f / (a1 * l + a0 * l0);
    a1 *= inv; a0 *= inv;
#pragma unroll
    for (int t = 0; t < 2; ++t)
#pragma unroll
      for (int r = 0; r < 16; ++r) {
        int d = (r & 3) + 8 * (r >> 2) + 4 * hi + 32 * t;
        ot[t][r] = a1 * ot[t][r] + a0 * Om[(pair * 64 + d) * 32 + l31];
      }
    uint32_t* Ow = (uint32_t*)&Om[pair * 64 * 32];
#pragma unroll
    for (int t = 0; t < 2; ++t)
#pragma unroll
      for (int g = 0; g < 4; ++g)
#pragma unroll
        for (int rp = 0; rp < 2; ++rp) {
          int r0 = 4 * g + 2 * rp;
          int ucol = rp + 4 * g + 2 * hi + 16 * t;   // (d>>1)
          Ow[l31 * 32 + (ucol ^ ((l31 & 7) << 2))] = cvtpk(ot[t][r0], ot[t][r0 + 1]);
        }
    const int bb = bh / H_, h = bh % H_;
#pragma unroll
    for (int i = 0; i < 4; ++i) {
      int chunk = i * 64 + lane;           // 256 chunks of 16B = 32 rows x 128B
      int q = chunk >> 3, cc = chunk & 7;
      i32x4 v = *(const i32x4*)&Ow[q * 32 + ((cc * 4) ^ ((q & 7) << 2))];
      *(i32x4*)&Oa[((size_t)bb * S_ + q0 + q) * D_ + h * 64 + cc * 8] = v;
    }
  }
}

// ---------------------------------------------------------------------------
extern "C" void kernel_launch(void* const* d_in, const int* in_sizes, int n_in,
                              void* d_out, int out_size, void* d_ws, size_t ws_size,
                              hipStream_t stream) {
  const float* x  = (const float*)d_in[0];
  const float* wq = (const float*)d_in[1];
  const float* bq = (const float*)d_in[2];
  const float* wk = (const float*)d_in[3];
  const float* bk = (const float*)d_in[4];
  const float* wv = (const float*)d_in[5];
  const float* bv = (const float*)d_in[6];
  const float* wo = (const float*)d_in[7];
  const float* bo = (const float*)d_in[8];

  const size_t XB = (size_t)M_ * D_;   // 6,291,456
  const size_t WB = (size_t)D_ * D_;   //   589,824
  ushort* xb    = (ushort*)d_ws;
  ushort* wqb   = xb + XB;
  ushort* wkb   = wqb + WB;
  ushort* wvb   = wkb + WB;
  ushort* wob   = wvb + WB;
  ushort* qb    = wob + WB;
  ushort* kbuf  = qb + XB;
  ushort* vtb   = kbuf + XB;
  ushort* attnb = vtb + XB;            // total ~67.6 MB

  cvt_f32_bf16<<<(int)(XB / 8 / 256), 256, 0, stream>>>(x, xb, (int)(XB / 8));
  cvtw_f32_bf16<<<dim3((int)(WB / 8 / 256), 4), 256, 0, stream>>>(
      wq, wk, wv, wo, wqb, wkb, wvb, wob, (int)(WB / 8));

  gemm_qkv<<<dim3(M_ / 128, 18), 256, 0, stream>>>(xb, wqb, wkb, wvb,
                                                   bq, bk, bv, qb, kbuf, vtb);
  attn_fwd5<<<dim3(B_ * H_, S_ / 128), 512, 0, stream>>>(qb, kbuf, vtb, attnb);
  gemm_out<<<dim3(M_ / 64, D_ / 128), 256, 0, stream>>>(attnb, wob, bo, (float*)d_out);
}

// Round 8
// 137.179 us; speedup vs baseline: 2.3668x; 1.0546x over previous
//
#include <hip/hip_runtime.h>
#include <hip/hip_bf16.h>
#include <cstdint>

// B=4, S=2048, D=768, H=12, DK=64. All fp32 in/out; bf16 MFMA compute inside.
static constexpr int B_ = 4, S_ = 2048, D_ = 768, H_ = 12, DK_ = 64;
static constexpr int M_ = B_ * S_;  // 8192 rows of x / attn

typedef short bf16x4 __attribute__((ext_vector_type(4)));
typedef short bf16x8 __attribute__((ext_vector_type(8)));   // 8 bf16 = 4 VGPRs
typedef float f32x4 __attribute__((ext_vector_type(4)));
typedef float f32x16 __attribute__((ext_vector_type(16)));
typedef int i32x4 __attribute__((ext_vector_type(4)));

#define MFMA16(a, b, c) __builtin_amdgcn_mfma_f32_16x16x32_bf16((a), (b), (c), 0, 0, 0)
#define MFMA32(a, b, c) __builtin_amdgcn_mfma_f32_32x32x16_bf16((a), (b), (c), 0, 0, 0)

__device__ inline ushort f2bf(float f) {
  uint32_t u = __float_as_uint(f);
  u += 0x7fffu + ((u >> 16) & 1u);  // round-nearest-even
  return (ushort)(u >> 16);
}
__device__ inline uint32_t pkbf(float a, float b) {
  return (uint32_t)f2bf(a) | ((uint32_t)f2bf(b) << 16);
}
// hardware packed f32->bf16 (RNE)
__device__ inline uint32_t cvtpk(float lo, float hi) {
  uint32_t r;
  asm("v_cvt_pk_bf16_f32 %0, %1, %2" : "=v"(r) : "v"(lo), "v"(hi));
  return r;
}
// async global->LDS, 16B per lane (LDS dest = wave-uniform base + lane*16)
__device__ inline void gload_lds16(const void* g, void* l) {
  __builtin_amdgcn_global_load_lds((const __attribute__((address_space(1))) void*)g,
                                   (__attribute__((address_space(3))) void*)l, 16, 0, 0);
}

// ---------------- fp32 -> bf16 convert (8 elems/thread, 16B store) ----------
__global__ void cvt_f32_bf16(const float* __restrict__ in, ushort* __restrict__ out, int n8) {
  int i = blockIdx.x * 256 + threadIdx.x;
  if (i >= n8) return;
  const float4* p = (const float4*)in;
  float4 v0 = p[2 * i], v1 = p[2 * i + 1];
  ((uint4*)out)[i] = make_uint4(pkbf(v0.x, v0.y), pkbf(v0.z, v0.w),
                                pkbf(v1.x, v1.y), pkbf(v1.z, v1.w));
}

// 4 weight matrices in one launch (blockIdx.y selects)
__global__ void cvtw_f32_bf16(const float* __restrict__ w0, const float* __restrict__ w1,
                              const float* __restrict__ w2, const float* __restrict__ w3,
                              ushort* __restrict__ o0, ushort* __restrict__ o1,
                              ushort* __restrict__ o2, ushort* __restrict__ o3, int n8) {
  const float* in;
  ushort* out;
  switch (blockIdx.y) {
    case 0: in = w0; out = o0; break;
    case 1: in = w1; out = o1; break;
    case 2: in = w2; out = o2; break;
    default: in = w3; out = o3; break;
  }
  int i = blockIdx.x * 256 + threadIdx.x;
  if (i >= n8) return;
  const float4* p = (const float4*)in;
  float4 v0 = p[2 * i], v1 = p[2 * i + 1];
  ((uint4*)out)[i] = make_uint4(pkbf(v0.x, v0.y), pkbf(v0.z, v0.w),
                                pkbf(v1.x, v1.y), pkbf(v1.z, v1.w));
}

// ---------------- fused QKV GEMM: 2-phase dbuf + coalesced LDS epilogue -----
// blockIdx.y in [0,18): wsel = y/6 selects {Wq->Q, Wk->K, Wv->V^T}.
// V blocks compute the C-tile TRANSPOSED (swap MFMA operands: fragment
// layouts of A and B are symmetric) so every mode's output is row-run
// contiguous; epilogue stages the 128x128 bf16 tile in the (now free)
// 32KB LDS with an XOR swizzle and stores 16B/lane fully coalesced.
__global__ __launch_bounds__(256) void gemm_qkv(const ushort* __restrict__ A,
                                                const ushort* __restrict__ Wq,
                                                const ushort* __restrict__ Wk,
                                                const ushort* __restrict__ Wv,
                                                const float* __restrict__ bqp,
                                                const float* __restrict__ bkp,
                                                const float* __restrict__ bvp,
                                                ushort* __restrict__ Qo,
                                                ushort* __restrict__ Ko,
                                                ushort* __restrict__ Vo) {
  constexpr int K = D_;   // 768
  constexpr int BK = 32;
  constexpr int NT = K / BK;  // 24
  __shared__ ushort SMEM[4][128 * BK];   // 32KB: As=SMEM[0..1], Bs=SMEM[2..3]

  const int wsel = blockIdx.y / 6;
  const int bn = (blockIdx.y % 6) * 128;
  const ushort* Bw = wsel == 0 ? Wq : wsel == 1 ? Wk : Wv;
  const float* bias = wsel == 0 ? bqp : wsel == 1 ? bkp : bvp;
  ushort* outp = wsel == 0 ? Qo : wsel == 1 ? Ko : Vo;

  const int tid = threadIdx.x;
  const int lane = tid & 63, w = tid >> 6;
  const int wr = w >> 1, wc = w & 1;
  const int l15 = lane & 15, l4 = lane >> 4;
  const int bm = blockIdx.x * 128;

  f32x4 acc[4][4] = {};

  auto stage = [&](int buf, int k0) {
#pragma unroll
    for (int i = 0; i < 2; ++i) {
      int e = (i * 256 + tid) * 8;
      int r = e >> 5, c = e & 31;
      gload_lds16(&A[(size_t)(bm + r) * K + k0 + c], &SMEM[buf][e]);
      gload_lds16(&Bw[(size_t)(bn + r) * K + k0 + c], &SMEM[2 + buf][e]);
    }
  };

  stage(0, 0);
  __syncthreads();           // buf0 ready
  int cur = 0;
  for (int t = 0; t < NT; ++t) {
    if (t + 1 < NT) stage(cur ^ 1, (t + 1) * BK);   // prefetch next tile
    bf16x8 a[4], b[4];
#pragma unroll
    for (int mi = 0; mi < 4; ++mi)
      a[mi] = *(const bf16x8*)&SMEM[cur][(wr * 64 + mi * 16 + l15) * BK + l4 * 8];
#pragma unroll
    for (int ni = 0; ni < 4; ++ni)
      b[ni] = *(const bf16x8*)&SMEM[2 + cur][(wc * 64 + ni * 16 + l15) * BK + l4 * 8];
    __builtin_amdgcn_s_setprio(1);
    if (wsel < 2) {
#pragma unroll
      for (int mi = 0; mi < 4; ++mi)
#pragma unroll
        for (int ni = 0; ni < 4; ++ni)
          acc[mi][ni] = MFMA16(a[mi], b[ni], acc[mi][ni]);
    } else {   // transposed C: D[row=N][col=M]
#pragma unroll
      for (int mi = 0; mi < 4; ++mi)
#pragma unroll
        for (int ni = 0; ni < 4; ++ni)
          acc[mi][ni] = MFMA16(b[ni], a[mi], acc[mi][ni]);
    }
    __builtin_amdgcn_s_setprio(0);
    __syncthreads();         // next-tile loads landed; cur free for overwrite
    cur ^= 1;
  }

  // ---- epilogue: stage bf16 C-tile in LDS (XOR swizzle), coalesced store ---
  // wsel<2: lr = M-local (s), lc = N-local. wsel==2: lr = N-local, lc = M-local.
  ushort* Cst = &SMEM[0][0];     // 16384 ushorts = 128 rows x 128 cols
#pragma unroll
  for (int ni = 0; ni < 4; ++ni) {
    float bv[4];
    if (wsel < 2) {
      float bc = bias[bn + wc * 64 + ni * 16 + l15];
#pragma unroll
      for (int r = 0; r < 4; ++r) bv[r] = bc;
    } else {
#pragma unroll
      for (int r = 0; r < 4; ++r) bv[r] = bias[bn + wc * 64 + ni * 16 + l4 * 4 + r];
    }
#pragma unroll
    for (int mi = 0; mi < 4; ++mi)
#pragma unroll
      for (int r = 0; r < 4; ++r) {
        int lr, lc;
        if (wsel < 2) { lr = wr * 64 + mi * 16 + l4 * 4 + r; lc = wc * 64 + ni * 16 + l15; }
        else          { lr = wc * 64 + ni * 16 + l4 * 4 + r; lc = wr * 64 + mi * 16 + l15; }
        Cst[lr * 128 + (lc ^ ((lr & 3) << 4))] = f2bf(acc[mi][ni][r] + bv[r]);
      }
  }
  __syncthreads();
  const int bbV = bm >> 11;      // batch (wsel==2 path): cc*8 < 128 so constant
#pragma unroll
  for (int it = 0; it < 8; ++it) {
    int chunk = it * 256 + tid;            // 2048 chunks of 16B
    int lr = chunk >> 4, cc = chunk & 15;
    i32x4 v = *(const i32x4*)&Cst[lr * 128 + ((cc * 8) ^ ((lr & 3) << 4))];
    if (wsel < 2) {
      int gr = bm + lr;                    // global M row
      int b0 = gr >> 11, s = gr & 2047;
      int gc = bn + cc * 8;                // global N col
      int h = gc >> 6, dk0 = gc & 63;
      *(i32x4*)&outp[((((size_t)b0 * H_ + h) * S_ + s) << 6) + dk0] = v;
    } else {
      int gn = bn + lr;                    // global N row: h*64+dk
      int h = gn >> 6, dk = gn & 63;
      int s0 = (bm & 2047) + cc * 8;
      *(i32x4*)&outp[(((size_t)bbV * H_ + h) * 64 + dk) * S_ + s0] = v;
    }
  }
}

// ---------------- output GEMM: 64x128 tiles, 2-phase dbuf, fp32 out ---------
__global__ __launch_bounds__(256) void gemm_out(const ushort* __restrict__ A,
                                                const ushort* __restrict__ Bw,
                                                const float* __restrict__ bias,
                                                float* __restrict__ outp) {
  constexpr int K = D_;
  constexpr int BK = 32;
  constexpr int NT = K / BK;
  __shared__ ushort As[2][64 * BK];
  __shared__ ushort Bs[2][128 * BK];

  const int tid = threadIdx.x;
  const int lane = tid & 63, w = tid >> 6;
  const int wr = w >> 1, wc = w & 1;           // wave tile: 32 rows x 64 cols
  const int l15 = lane & 15, l4 = lane >> 4;
  const int bm = blockIdx.x * 64, bn = blockIdx.y * 128;

  f32x4 acc[2][4] = {};

  auto stage = [&](int buf, int k0) {
    {
      int e = tid * 8;                          // A: 64x32 = 2048 elems
      int r = e >> 5, c = e & 31;
      gload_lds16(&A[(size_t)(bm + r) * K + k0 + c], &As[buf][e]);
    }
#pragma unroll
    for (int i = 0; i < 2; ++i) {               // B: 128x32 = 4096 elems
      int e = (i * 256 + tid) * 8;
      int r = e >> 5, c = e & 31;
      gload_lds16(&Bw[(size_t)(bn + r) * K + k0 + c], &Bs[buf][e]);
    }
  };

  stage(0, 0);
  __syncthreads();
  int cur = 0;
  for (int t = 0; t < NT; ++t) {
    if (t + 1 < NT) stage(cur ^ 1, (t + 1) * BK);
    bf16x8 a[2], b[4];
#pragma unroll
    for (int mi = 0; mi < 2; ++mi)
      a[mi] = *(const bf16x8*)&As[cur][(wr * 32 + mi * 16 + l15) * BK + l4 * 8];
#pragma unroll
    for (int ni = 0; ni < 4; ++ni)
      b[ni] = *(const bf16x8*)&Bs[cur][(wc * 64 + ni * 16 + l15) * BK + l4 * 8];
    __builtin_amdgcn_s_setprio(1);
#pragma unroll
    for (int mi = 0; mi < 2; ++mi)
#pragma unroll
      for (int ni = 0; ni < 4; ++ni)
        acc[mi][ni] = MFMA16(a[mi], b[ni], acc[mi][ni]);
    __builtin_amdgcn_s_setprio(0);
    __syncthreads();
    cur ^= 1;
  }

#pragma unroll
  for (int mi = 0; mi < 2; ++mi)
#pragma unroll
    for (int ni = 0; ni < 4; ++ni) {
      int col = bn + wc * 64 + ni * 16 + l15;
      float bv = bias[col];
#pragma unroll
      for (int r = 0; r < 4; ++r) {
        int row = bm + wr * 32 + mi * 16 + l4 * 4 + r;
        outp[(size_t)row * D_ + col] = acc[mi][ni][r] + bv;
      }
    }
}

// ---------------- causal flash attention: 8 waves, sub-tile KV-split --------
// (unchanged from round 6 — attribution: this round only changes gemm_qkv)
__global__ __launch_bounds__(512) void attn_fwd5(const ushort* __restrict__ Q,
                                                 const ushort* __restrict__ Kg,
                                                 const ushort* __restrict__ Vt,
                                                 ushort* __restrict__ Oa) {
  __shared__ ushort KVb[2][2][64 * 64];       // [kind K/V][buf][tile] = 32KB
  __shared__ float Ml[4][32], Ll[4][32];

  const int bh = blockIdx.x;
  const int w = threadIdx.x >> 6, lane = threadIdx.x & 63;
  const int l31 = lane & 31, hi = lane >> 5;
  const int pair = w >> 1, sp = w & 1;
  const int qtb = gridDim.y - 1 - blockIdx.y;      // heavy blocks first
  const int qb = qtb * 128;
  const int q0 = qb + pair * 32;

  const ushort* Qb = Q + (size_t)bh * (S_ * DK_);
  const char* Kc = (const char*)(Kg + (size_t)bh * (S_ * DK_));
  const char* Vc = (const char*)(Vt + (size_t)bh * (DK_ * S_));
  char* kKT = (char*)&KVb[0][0][0];
  char* kVT = (char*)&KVb[1][0][0];

  bf16x8 qf[4];
#pragma unroll
  for (int kc = 0; kc < 4; ++kc)
    qf[kc] = *(const bf16x8*)&Qb[(q0 + l31) * 64 + kc * 16 + hi * 8];

  f32x16 ot[2] = {};                 // O^T: row d=(r&3)+8*(r>>2)+4*hi+32t, col q=l31
  float m = -__builtin_inff(), l = 0.f;
  const float C = 0.125f * 1.4426950408889634f;  // 1/sqrt(64) * log2(e)
  const float THR = 8.0f / C;

  auto stage = [&](int buf, int kt) {
    const int k0 = kt * 64;
    int obase = w * 1024;
    int o = obase + lane * 16;
    int mk = ((o >> 7) & 7) << 4;                  // XOR swizzle (rule #21)
    gload_lds16(Kc + (size_t)k0 * 128 + (o ^ mk), kKT + buf * 8192 + obase);
    int d = o >> 7, colb = (o & 127) ^ mk;
    gload_lds16(Vc + (size_t)d * 4096 + (size_t)k0 * 2 + colb, kVT + buf * 8192 + obase);
  };

  const int nkt = qb / 64 + 2;       // walk keys [0, qb+128)
  int cur = 0;
  stage(0, 0);
  __syncthreads();

  for (int kt = 0; kt < nkt; ++kt) {
    if (kt + 1 < nkt) stage(cur ^ 1, kt + 1);
    const int ks = kt * 64 + sp * 32;
    if (ks <= q0 + 31) {             // wave-uniform
      const char* KTc = kKT + cur * 8192;
      const char* VTc = kVT + cur * 8192;
      f32x16 st = {};
      __builtin_amdgcn_s_setprio(1);
#pragma unroll
      for (int kc = 0; kc < 4; ++kc) {
        int row = sp * 32 + l31;
        int col = (kc * 32 + hi * 16) ^ ((row & 7) << 4);
        bf16x8 kf = *(const bf16x8*)(KTc + row * 128 + col);
        st = MFMA32(kf, qf[kc], st);
      }
      __builtin_amdgcn_s_setprio(0);
      if (ks + 31 > q0) {
#pragma unroll
        for (int r = 0; r < 16; ++r) {
          int kr = ks + (r & 3) + 8 * (r >> 2) + 4 * hi;
          if (kr > q0 + l31) st[r] = -__builtin_inff();
        }
      }
      float mx[8];
#pragma unroll
      for (int i = 0; i < 8; ++i) mx[i] = fmaxf(st[i], st[i + 8]);
#pragma unroll
      for (int i = 0; i < 4; ++i) mx[i] = fmaxf(mx[i], mx[i + 4]);
      float pm = fmaxf(fmaxf(mx[0], mx[1]), fmaxf(mx[2], mx[3]));
      pm = fmaxf(pm, __shfl_xor(pm, 32, 64));
      if (!__all(pm <= m + THR)) {
        float mn = fmaxf(m, pm);
        float al = exp2f((m - mn) * C);
        m = mn;
        l *= al;
#pragma unroll
        for (int t = 0; t < 2; ++t)
#pragma unroll
          for (int r = 0; r < 16; ++r) ot[t][r] *= al;
      }
      const float mc = m * C;
#pragma unroll
      for (int r = 0; r < 16; ++r) st[r] = exp2f(fmaf(st[r], C, -mc));
      float sx[8];
#pragma unroll
      for (int i = 0; i < 8; ++i) sx[i] = st[i] + st[i + 8];
#pragma unroll
      for (int i = 0; i < 4; ++i) sx[i] = sx[i] + sx[i + 4];
      float rs = (sx[0] + sx[1]) + (sx[2] + sx[3]);
      rs += __shfl_xor(rs, 32, 64);
      l += rs;
      // zero-shuffle PV: B-frag = own St regs in order; V^T via 2x b64
#pragma unroll
      for (int c = 0; c < 2; ++c) {
        i32x4 bw;
        bw.x = (int)cvtpk(st[8 * c + 0], st[8 * c + 1]);
        bw.y = (int)cvtpk(st[8 * c + 2], st[8 * c + 3]);
        bw.z = (int)cvtpk(st[8 * c + 4], st[8 * c + 5]);
        bw.w = (int)cvtpk(st[8 * c + 6], st[8 * c + 7]);
        bf16x8 pf = __builtin_bit_cast(bf16x8, bw);
        __builtin_amdgcn_s_setprio(1);
#pragma unroll
        for (int t = 0; t < 2; ++t) {
          int row = t * 32 + l31;
          int swz = (row & 7) << 4;
          int colA = sp * 64 + c * 32 + hi * 8;
          bf16x4 vlo = *(const bf16x4*)(VTc + row * 128 + (colA ^ swz));
          bf16x4 vhi = *(const bf16x4*)(VTc + row * 128 + ((colA + 16) ^ swz));
          bf16x8 vf = __builtin_shufflevector(vlo, vhi, 0, 1, 2, 3, 4, 5, 6, 7);
          ot[t] = MFMA32(vf, pf, ot[t]);
        }
        __builtin_amdgcn_s_setprio(0);
      }
    }
    __syncthreads();
    cur ^= 1;
  }

  // ---- merge the two key-splits per pair (KV LDS reused as scratch) ----
  float* Om = (float*)&KVb[0][0][0];            // [4][64][32] f32 = 32KB
  if (sp == 0) {
#pragma unroll
    for (int t = 0; t < 2; ++t)
#pragma unroll
      for (int r = 0; r < 16; ++r) {
        int d = (r & 3) + 8 * (r >> 2) + 4 * hi + 32 * t;
        Om[(pair * 64 + d) * 32 + l31] = ot[t][r];
      }
    if (hi == 0) { Ml[pair][l31] = m; Ll[pair][l31] = l; }
  }
  __syncthreads();
  if (sp == 1) {
    float m0 = Ml[pair][l31], l0 = Ll[pair][l31];
    float M = fmaxf(m, m0);
    float a1 = exp2f((m - M) * C), a0 = exp2f((m0 - M) * C);
    float inv = 1.0f / (a1 * l + a0 * l0);
    a1 *= inv; a0 *= inv;
#pragma unroll
    for (int t = 0; t < 2; ++t)
#pragma unroll
      for (int r = 0; r < 16; ++r) {
        int d = (r & 3) + 8 * (r >> 2) + 4 * hi + 32 * t;
        ot[t][r] = a1 * ot[t][r] + a0 * Om[(pair * 64 + d) * 32 + l31];
      }
    uint32_t* Ow = (uint32_t*)&Om[pair * 64 * 32];
#pragma unroll
    for (int t = 0; t < 2; ++t)
#pragma unroll
      for (int g = 0; g < 4; ++g)
#pragma unroll
        for (int rp = 0; rp < 2; ++rp) {
          int r0 = 4 * g + 2 * rp;
          int ucol = rp + 4 * g + 2 * hi + 16 * t;   // (d>>1)
          Ow[l31 * 32 + (ucol ^ ((l31 & 7) << 2))] = cvtpk(ot[t][r0], ot[t][r0 + 1]);
        }
    const int bb = bh / H_, h = bh % H_;
#pragma unroll
    for (int i = 0; i < 4; ++i) {
      int chunk = i * 64 + lane;           // 256 chunks of 16B = 32 rows x 128B
      int q = chunk >> 3, cc = chunk & 7;
      i32x4 v = *(const i32x4*)&Ow[q * 32 + ((cc * 4) ^ ((q & 7) << 2))];
      *(i32x4*)&Oa[((size_t)bb * S_ + q0 + q) * D_ + h * 64 + cc * 8] = v;
    }
  }
}

// ---------------------------------------------------------------------------
extern "C" void kernel_launch(void* const* d_in, const int* in_sizes, int n_in,
                              void* d_out, int out_size, void* d_ws, size_t ws_size,
                              hipStream_t stream) {
  const float* x  = (const float*)d_in[0];
  const float* wq = (const float*)d_in[1];
  const float* bq = (const float*)d_in[2];
  const float* wk = (const float*)d_in[3];
  const float* bk = (const float*)d_in[4];
  const float* wv = (const float*)d_in[5];
  const float* bv = (const float*)d_in[6];
  const float* wo = (const float*)d_in[7];
  const float* bo = (const float*)d_in[8];

  const size_t XB = (size_t)M_ * D_;   // 6,291,456
  const size_t WB = (size_t)D_ * D_;   //   589,824
  ushort* xb    = (ushort*)d_ws;
  ushort* wqb   = xb + XB;
  ushort* wkb   = wqb + WB;
  ushort* wvb   = wkb + WB;
  ushort* wob   = wvb + WB;
  ushort* qb    = wob + WB;
  ushort* kbuf  = qb + XB;
  ushort* vtb   = kbuf + XB;
  ushort* attnb = vtb + XB;            // total ~67.6 MB

  cvt_f32_bf16<<<(int)(XB / 8 / 256), 256, 0, stream>>>(x, xb, (int)(XB / 8));
  cvtw_f32_bf16<<<dim3((int)(WB / 8 / 256), 4), 256, 0, stream>>>(
      wq, wk, wv, wo, wqb, wkb, wvb, wob, (int)(WB / 8));

  gemm_qkv<<<dim3(M_ / 128, 18), 256, 0, stream>>>(xb, wqb, wkb, wvb,
                                                   bq, bk, bv, qb, kbuf, vtb);
  attn_fwd5<<<dim3(B_ * H_, S_ / 128), 512, 0, stream>>>(qb, kbuf, vtb, attnb);
  gemm_out<<<dim3(M_ / 64, D_ / 128), 256, 0, stream>>>(attnb, wob, bo, (float*)d_out);
}